// Round 1
// 546.092 us; speedup vs baseline: 1.0015x; 1.0015x over previous
//
#include <hip/hip_runtime.h>
#include <hip/hip_bf16.h>

typedef __hip_bfloat16 bf16;
using short8  = __attribute__((ext_vector_type(8))) short;
using float4v = __attribute__((ext_vector_type(4))) float;

static constexpr int N_ = 50000;   // nodes
static constexpr int E_ = 20000;   // hyperedges
static constexpr int M_ = 320000;  // incidence pairs
static constexpr int NPAD_ = 50048;  // 391*128 rows for MFMA grid
static constexpr int NB_E = (E_+255)/256;   // 79
static constexpr int NB_N = (N_+255)/256;   // 196

__device__ __forceinline__ float b2f(bf16 v){ return __bfloat162float(v); }
__device__ __forceinline__ float sigm(float x){ return 1.f/(1.f+__expf(-x)); }
__device__ __forceinline__ float u2f(unsigned short u){ return __uint_as_float(((unsigned)u)<<16); }
__device__ __forceinline__ unsigned short f2u(float f){ bf16 t=__float2bfloat16(f); return *(unsigned short*)&t; }

// ---------------- dtype sniff ----------------
__global__ __launch_bounds__(256) void k_sniff(const unsigned short* __restrict__ xb, int* flag){
  int tid = threadIdx.x;
  int sane = 0;
  for (int i = tid; i < 4096; i += 256){
    unsigned short u = xb[2*i];
    int ex = (u >> 7) & 0xFF;
    if ((u & 0x7FFF) == 0 || (ex >= 117 && ex <= 137)) sane++;
  }
  #pragma unroll
  for (int d=1; d<64; d<<=1) sane += __shfl_xor(sane, d, 64);
  __shared__ int wsh[4];
  if ((tid&63)==0) wsh[tid>>6] = sane;
  __syncthreads();
  if (tid==0){
    int tot = wsh[0]+wsh[1]+wsh[2]+wsh[3];
    *flag = (tot > 2048) ? 1 : 0;    // 1 = bf16 storage
  }
}

// ---------------- converts ----------------
__global__ __launch_bounds__(256) void k_cvt16(const void* __restrict__ src, bf16* __restrict__ dst,
                                               int n, const int* __restrict__ flag){
  int i = blockIdx.x*256 + threadIdx.x;
  if (i >= n) return;
  if (*flag) dst[i] = ((const bf16*)src)[i];
  else       dst[i] = __float2bfloat16(((const float*)src)[i]);
}

// all 10 small weight tensors -> fp32, one launch
__global__ __launch_bounds__(256) void k_cvtall(
    const void* s0, const void* s1, const void* s2, const void* s3, const void* s4,
    const void* s5, const void* s6, const void* s7, const void* s8, const void* s9,
    float* d0, float* d1, float* d2, float* d3, float* d4,
    float* d5, float* d6, float* d7, float* d8, float* d9,
    const int* __restrict__ flag){
  int i = blockIdx.x*256 + threadIdx.x;
  const void* src; float* dst; int off;
  if      (i < 1536)            { src=s0; dst=d0; off=i; }
  else if (i < 1536+81920)      { src=s1; dst=d1; off=i-1536; }
  else if (i < 83712+256)       { src=s2; dst=d2; off=i-83712; }
  else if (i < 83968+256)       { src=s3; dst=d3; off=i-83968; }
  else if (i < 84224+8)         { src=s4; dst=d4; off=i-84224; }
  else if (i < 84232+131072)    { src=s5; dst=d5; off=i-84232; }
  else if (i < 215304+131072)   { src=s6; dst=d6; off=i-215304; }
  else if (i < 346376+1536)     { src=s7; dst=d7; off=i-346376; }
  else if (i < 347912+512)      { src=s8; dst=d8; off=i-347912; }
  else if (i < 348424+512)      { src=s9; dst=d9; off=i-348424; }
  else return;
  if (*flag) dst[off] = b2f(((const bf16*)src)[off]);
  else       dst[off] = ((const float*)src)[off];
}

__global__ __launch_bounds__(256) void k_zero2(int* pe, int* pn){
  int i = blockIdx.x*256 + threadIdx.x;
  if (i < E_) pe[i] = 0;
  else if (i < E_+N_) pn[i-E_] = 0;
}

// ---------------- CSR build ----------------
__global__ __launch_bounds__(256) void k_hist(const int* __restrict__ eidx, const int* __restrict__ nidx,
                                              int* cnt_e, int* cnt_n){
  int m = blockIdx.x*256 + threadIdx.x;
  if (m < M_){ atomicAdd(&cnt_e[eidx[m]],1); atomicAdd(&cnt_n[nidx[m]],1); }
}

__device__ __forceinline__ void scan1_body(const int* cnt, int* off, int* bsum, int n, int blk){
  int tid = threadIdx.x, lane = tid&63, wid = tid>>6;
  int i = blk*256 + tid;
  int v = (i<n)? cnt[i] : 0;
  int s = v;
  #pragma unroll
  for (int d=1; d<64; d<<=1){ int t = __shfl_up(s, d, 64); if (lane>=d) s += t; }
  __shared__ int ws[4]; __shared__ int wo[4];
  if (lane==63) ws[wid] = s;
  __syncthreads();
  if (tid==0){ int a=0; for (int k=0;k<4;k++){ int t=ws[k]; wo[k]=a; a+=t; } bsum[blk]=a; }
  __syncthreads();
  if (i<n) off[i] = wo[wid] + s - v;
}

__global__ __launch_bounds__(256) void k_scan1m(const int* __restrict__ cnt_e, int* __restrict__ eoff, int* bsum_e,
                                                const int* __restrict__ cnt_n, int* __restrict__ noff, int* bsum_n){
  int b = blockIdx.x;
  if (b < NB_E) scan1_body(cnt_e, eoff, bsum_e, E_, b);
  else          scan1_body(cnt_n, noff, bsum_n, N_, b-NB_E);
}

__device__ __forceinline__ void scan2_body(int* bsum, int* off, int nb, int n){
  int tid = threadIdx.x, lane = tid&63, wid = tid>>6;
  int v = (tid<nb)? bsum[tid] : 0;
  int s = v;
  #pragma unroll
  for (int d=1; d<64; d<<=1){ int t = __shfl_up(s, d, 64); if (lane>=d) s += t; }
  __shared__ int ws[4]; __shared__ int wo[4];
  if (lane==63) ws[wid] = s;
  __syncthreads();
  if (tid==0){ int a=0; for (int k=0;k<4;k++){ int t=ws[k]; wo[k]=a; a+=t; } off[n]=a; }
  __syncthreads();
  if (tid<nb) bsum[tid] = wo[wid] + s - v;
}

__global__ __launch_bounds__(256) void k_scan2m(int* bsum_e, int* __restrict__ eoff,
                                                int* bsum_n, int* __restrict__ noff){
  if (blockIdx.x == 0) scan2_body(bsum_e, eoff, NB_E, E_);
  else                 scan2_body(bsum_n, noff, NB_N, N_);
}

__global__ __launch_bounds__(256) void k_scan3m(const int* __restrict__ bsum_e, int* __restrict__ eoff, int* cur_e,
                                                const int* __restrict__ bsum_n, int* __restrict__ noff, int* cur_n){
  int b = blockIdx.x;
  if (b < NB_E){
    int i = b*256 + threadIdx.x;
    if (i<E_){ int e = eoff[i] + bsum_e[b]; eoff[i]=e; cur_e[i]=e; }
  } else {
    int i = (b-NB_E)*256 + threadIdx.x;
    if (i<N_){ int e = noff[i] + bsum_n[b-NB_E]; noff[i]=e; cur_n[i]=e; }
  }
}

__global__ __launch_bounds__(256) void k_fill(const int* __restrict__ eidx, const int* __restrict__ nidx,
                                              int* cur_e, int* cur_n, int* ep, int* np){
  int m = blockIdx.x*256 + threadIdx.x;
  if (m < M_){
    int p = atomicAdd(&cur_e[eidx[m]],1); ep[p]=m;
    int q = atomicAdd(&cur_n[nidx[m]],1); np[q]=m;
  }
}

// ---------------- pre / wqe / bpack ----------------
__global__ __launch_bounds__(256) void k_pre(const float* __restrict__ tq, const float* __restrict__ w1,
                                             const float* __restrict__ b1, float* __restrict__ pre){
  int idx = blockIdx.x*256 + threadIdx.x;
  if (idx >= 768) return;
  int l = idx / 384, r = idx % 384;
  int t = r / 128, r2 = r % 128;
  int h = r2 >> 5, k = r2 & 31;
  const float* tp = tq + ((l*4+h)*3 + t)*64;
  const float* wp = w1 + (size_t)((l*4+h)*32 + k)*320 + 256;
  float s = b1[(l*4+h)*32 + k];
  for (int d=0; d<64; ++d) s += tp[d]*wp[d];
  pre[(l*3+t)*128 + r2] = s;
}

__global__ __launch_bounds__(256) void k_wqe(const float* __restrict__ wq_f, const float* __restrict__ ec_f,
                                             float* __restrict__ wqe){
  int b = blockIdx.x;
  int l = b/12, ht = b%12, h = ht/3, t = ht%3;
  int d = threadIdx.x;
  const float* ecp = ec_f + ((l*4+h)*3 + t)*64;
  const float* wqp = wq_f + (size_t)((l*4+h)*64)*256;
  float s = 0.f;
  for (int o=0;o<64;++o) s += ecp[o]*wqp[o*256 + d];
  wqe[(size_t)(l*12+ht)*256 + d] = s;
}

// pack B panel with V cols PERMUTED to the V16 interleave order
__global__ __launch_bounds__(256) void k_bpack(const float* __restrict__ wv_f, const float* __restrict__ w1_f,
                                               const float* __restrict__ wqe, bf16* __restrict__ Bp){
  int idx = blockIdx.x*256 + threadIdx.x;
  if (idx >= 2*448*256) return;
  int l = idx / (448*256), r = idx % (448*256);
  int c = r >> 8, k = r & 255;
  float v = 0.f;
  if (c < 256){
    int dd = c >> 2, h = c & 3;
    v = wv_f[(size_t)l*65536 + (size_t)(h*64+dd)*256 + k];
  }
  else if (c < 384) v = w1_f[(size_t)l*40960 + (size_t)(c-256)*320 + k];
  else if (c < 396) v = wqe[(size_t)(l*12 + c-384)*256 + k];
  Bp[idx] = __float2bfloat16(v);
}

// ---------------- MFMA GEMM, XCD-swizzled, FULL-K register staging ----------------
// K=256 = 4 stages of 64. All 48 16B loads per lane issued up front (sched_barrier
// pins them before any MFMA), so each wave keeps ~48KB in flight -> HBM-throughput
// bound, not latency bound. launch_bounds(256,2): 256-VGPR budget so all 48 dest
// quads (192 VGPR) + 8 acc float4 (32) stay in registers. x=kk%7 keeps the 7
// consumers of one 64KB A-panel adjacent on their XCD -> A stays L2-resident.
__global__ __launch_bounds__(256,2) void k_mgemm(const bf16* __restrict__ A16, const bf16* __restrict__ Bp,
    bf16* __restrict__ V16, bf16* __restrict__ Hb16, float* __restrict__ S){
  int g = blockIdx.x;
  int r8 = g & 7, kk = g >> 3;
  int x = kk % 7, yhi = kk / 7;
  int y = yhi*8 + r8;
  if (y >= 391 || x >= 7) return;
  int wid = threadIdx.x >> 6, lane = threadIdx.x & 63;
  int q = lane >> 4, li = lane & 15;
  int row0 = y*128 + wid*32;
  int col0 = x*64;
  float4v acc[2][4];
  #pragma unroll
  for (int i=0;i<2;i++)
    #pragma unroll
    for (int j=0;j<4;j++) acc[i][j] = (float4v)(0.f);
  const bf16* a0p = A16 + (size_t)(row0 + li)*256 + q*8;
  const bf16* a1p = A16 + (size_t)(row0 + 16 + li)*256 + q*8;
  const bf16* bp  = Bp  + (size_t)(col0 + li)*256 + q*8;

  short8 bA0[4][2], bA1[4][2], bB[4][4][2];   // [stage][k-half], B:[stage][j][k-half]
  #pragma unroll
  for (int st=0; st<4; ++st){
    int ko = st*64;
    bA0[st][0] = *(const short8*)(a0p + ko);  bA0[st][1] = *(const short8*)(a0p + ko + 32);
    bA1[st][0] = *(const short8*)(a1p + ko);  bA1[st][1] = *(const short8*)(a1p + ko + 32);
    #pragma unroll
    for (int j=0;j<4;j++){
      bB[st][j][0] = *(const short8*)(bp + j*16*256 + ko);
      bB[st][j][1] = *(const short8*)(bp + j*16*256 + ko + 32);
    }
  }
  __builtin_amdgcn_sched_barrier(0);   // pin: all 48 loads issued before any MFMA
  #pragma unroll
  for (int st=0; st<4; ++st){
    #pragma unroll
    for (int kh=0; kh<2; ++kh){
      #pragma unroll
      for (int j=0;j<4;j++){
        acc[0][j] = __builtin_amdgcn_mfma_f32_16x16x32_bf16(bA0[st][kh], bB[st][j][kh], acc[0][j],0,0,0);
        acc[1][j] = __builtin_amdgcn_mfma_f32_16x16x32_bf16(bA1[st][kh], bB[st][j][kh], acc[1][j],0,0,0);
      }
    }
  }
  #pragma unroll
  for (int i=0;i<2;i++){
    #pragma unroll
    for (int r=0;r<4;r++){
      int grow = row0 + i*16 + q*4 + r;
      if (grow >= N_) continue;
      #pragma unroll
      for (int j=0;j<4;j++){
        int gc = col0 + j*16 + li;
        float v = acc[i][j][r];
        if (gc < 256)      V16 [(size_t)grow*256 + gc]       = __float2bfloat16(v);  // contiguous (permuted)
        else if (gc < 384) Hb16[(size_t)grow*128 + gc - 256] = __float2bfloat16(v);
        else if (gc < 396) S   [(size_t)grow*12  + gc - 384] = v;
      }
    }
  }
}

// ---------------- per-node gate (Hb bf16) ----------------
__global__ __launch_bounds__(256) void k_gate(const unsigned short* __restrict__ Hb16, const float* __restrict__ S,
    const float* __restrict__ pre_l, const float* __restrict__ w2_l, const float* __restrict__ b2_l,
    const int* __restrict__ ntype, float* __restrict__ G){
  int node = blockIdx.x*4 + (threadIdx.x>>6);
  int lane = threadIdx.x & 63;
  if (node >= N_) return;
  int typ = ntype[node];
  const float* pr = pre_l + typ*128;
  float v0 = tanhf(u2f(Hb16[(size_t)node*128 + lane])      + pr[lane]);
  float v1 = tanhf(u2f(Hb16[(size_t)node*128 + 64 + lane]) + pr[64+lane]);
  float p0 = v0 * w2_l[lane];
  float p1 = v1 * w2_l[64+lane];
  #pragma unroll
  for (int d=1; d<32; d<<=1){ p0 += __shfl_xor(p0,d,64); p1 += __shfl_xor(p1,d,64); }
  float at0 = sigm(__shfl(p0, 0,64) + b2_l[0]);
  float at1 = sigm(__shfl(p0,32,64) + b2_l[1]);
  float at2 = sigm(__shfl(p1, 0,64) + b2_l[2]);
  float at3 = sigm(__shfl(p1,32,64) + b2_l[3]);
  if (lane < 12){
    int h = lane / 3, t = lane % 3;
    float sv = S[(size_t)node*12 + lane];
    float lr = (sv > 0.f) ? sv : 0.2f*sv;
    float av = (h==0)? at0 : (h==1)? at1 : (h==2)? at2 : at3;
    G[(size_t)node*12 + t*4 + h] = lr * av;
  }
}

// ---------------- per-edge softmax + edge_feat (single-pass, pipelined gather) ----------------
__global__ __launch_bounds__(256) void k_edge(const int* __restrict__ eoff, const int* __restrict__ ep,
    const int* __restrict__ nidx, const int* __restrict__ etype,
    const float* __restrict__ G, const unsigned short* __restrict__ V16,
    float* __restrict__ attn, unsigned short* __restrict__ EF16){
  int e = blockIdx.x*4 + (threadIdx.x>>6);
  int lane = threadIdx.x & 63;
  if (e >= E_) return;
  int beg = eoff[e], end = eoff[e+1];
  int deg = end - beg;
  if (deg == 0) return;
  int t = etype[e];
  float a0=0,a1=0,a2=0,a3=0;

  if (deg <= 64){
    int i = beg + lane;
    int m = -1, n = 0;
    float4 g; g.x=g.y=g.z=g.w=-1e30f;
    if (lane < deg){
      m = ep[i]; n = nidx[m];
      g = *(const float4*)(G + (size_t)n*12 + t*4);
    }
    float mx0=g.x, mx1=g.y, mx2=g.z, mx3=g.w;
    #pragma unroll
    for (int d=1; d<64; d<<=1){
      mx0=fmaxf(mx0,__shfl_xor(mx0,d,64)); mx1=fmaxf(mx1,__shfl_xor(mx1,d,64));
      mx2=fmaxf(mx2,__shfl_xor(mx2,d,64)); mx3=fmaxf(mx3,__shfl_xor(mx3,d,64));
    }
    float ex0=0,ex1=0,ex2=0,ex3=0;
    if (lane < deg){
      ex0=__expf(g.x-mx0); ex1=__expf(g.y-mx1); ex2=__expf(g.z-mx2); ex3=__expf(g.w-mx3);
    }
    float s0=ex0,s1=ex1,s2=ex2,s3=ex3;
    #pragma unroll
    for (int d=1; d<64; d<<=1){
      s0+=__shfl_xor(s0,d,64); s1+=__shfl_xor(s1,d,64);
      s2+=__shfl_xor(s2,d,64); s3+=__shfl_xor(s3,d,64);
    }
    float4 w; w.x=ex0/s0; w.y=ex1/s1; w.z=ex2/s2; w.w=ex3/s3;
    if (lane < deg) *(float4*)(attn + (size_t)m*4) = w;
    auto ldrow = [&](int j)->ushort4{
      int nn = __shfl(n, j, 64);
      return *(const ushort4*)(V16 + (size_t)nn*256 + (lane<<2));
    };
    ushort4 v0v,v1v,v2v,v3v;
    if (deg>0) v0v=ldrow(0);
    if (deg>1) v1v=ldrow(1);
    if (deg>2) v2v=ldrow(2);
    if (deg>3) v3v=ldrow(3);
    for (int j=0;j<deg;j+=4){
      { float wx=__shfl(w.x,j,64),wy=__shfl(w.y,j,64),wz=__shfl(w.z,j,64),wq=__shfl(w.w,j,64);
        a0+=wx*u2f(v0v.x); a1+=wy*u2f(v0v.y); a2+=wz*u2f(v0v.z); a3+=wq*u2f(v0v.w);
        if (j+4<deg) v0v=ldrow(j+4); }
      if (j+1<deg){
        float wx=__shfl(w.x,j+1,64),wy=__shfl(w.y,j+1,64),wz=__shfl(w.z,j+1,64),wq=__shfl(w.w,j+1,64);
        a0+=wx*u2f(v1v.x); a1+=wy*u2f(v1v.y); a2+=wz*u2f(v1v.z); a3+=wq*u2f(v1v.w);
        if (j+5<deg) v1v=ldrow(j+5); }
      if (j+2<deg){
        float wx=__shfl(w.x,j+2,64),wy=__shfl(w.y,j+2,64),wz=__shfl(w.z,j+2,64),wq=__shfl(w.w,j+2,64);
        a0+=wx*u2f(v2v.x); a1+=wy*u2f(v2v.y); a2+=wz*u2f(v2v.z); a3+=wq*u2f(v2v.w);
        if (j+6<deg) v2v=ldrow(j+6); }
      if (j+3<deg){
        float wx=__shfl(w.x,j+3,64),wy=__shfl(w.y,j+3,64),wz=__shfl(w.z,j+3,64),wq=__shfl(w.w,j+3,64);
        a0+=wx*u2f(v3v.x); a1+=wy*u2f(v3v.y); a2+=wz*u2f(v3v.z); a3+=wq*u2f(v3v.w);
        if (j+7<deg) v3v=ldrow(j+7); }
    }
  } else {
    float mx0=-1e30f, mx1=-1e30f, mx2=-1e30f, mx3=-1e30f;
    for (int i=beg+lane; i<end; i+=64){
      int m = ep[i]; int n = nidx[m];
      float4 g = *(const float4*)(G + (size_t)n*12 + t*4);
      mx0=fmaxf(mx0,g.x); mx1=fmaxf(mx1,g.y); mx2=fmaxf(mx2,g.z); mx3=fmaxf(mx3,g.w);
    }
    #pragma unroll
    for (int d=1; d<64; d<<=1){
      mx0=fmaxf(mx0,__shfl_xor(mx0,d,64)); mx1=fmaxf(mx1,__shfl_xor(mx1,d,64));
      mx2=fmaxf(mx2,__shfl_xor(mx2,d,64)); mx3=fmaxf(mx3,__shfl_xor(mx3,d,64));
    }
    float sm0=0,sm1=0,sm2=0,sm3=0;
    for (int i=beg+lane; i<end; i+=64){
      int m = ep[i]; int n = nidx[m];
      float4 g = *(const float4*)(G + (size_t)n*12 + t*4);
      sm0+=__expf(g.x-mx0); sm1+=__expf(g.y-mx1); sm2+=__expf(g.z-mx2); sm3+=__expf(g.w-mx3);
    }
    #pragma unroll
    for (int d=1; d<64; d<<=1){
      sm0+=__shfl_xor(sm0,d,64); sm1+=__shfl_xor(sm1,d,64);
      sm2+=__shfl_xor(sm2,d,64); sm3+=__shfl_xor(sm3,d,64);
    }
    float inv0=1.f/sm0, inv1=1.f/sm1, inv2=1.f/sm2, inv3=1.f/sm3;
    for (int i=beg+lane; i<end; i+=64){
      int m = ep[i]; int n = nidx[m];
      float4 g = *(const float4*)(G + (size_t)n*12 + t*4);
      float4 w;
      w.x=__expf(g.x-mx0)*inv0; w.y=__expf(g.y-mx1)*inv1;
      w.z=__expf(g.z-mx2)*inv2; w.w=__expf(g.w-mx3)*inv3;
      *(float4*)(attn + (size_t)m*4) = w;
    }
    for (int i=beg; i<end; ++i){
      int m = ep[i]; int n = nidx[m];
      float4 g = *(const float4*)(G + (size_t)n*12 + t*4);
      float w0=__expf(g.x-mx0)*inv0, w1=__expf(g.y-mx1)*inv1;
      float w2=__expf(g.z-mx2)*inv2, w3=__expf(g.w-mx3)*inv3;
      ushort4 v = *(const ushort4*)(V16 + (size_t)n*256 + lane*4);
      a0 += w0*u2f(v.x); a1 += w1*u2f(v.y); a2 += w2*u2f(v.z); a3 += w3*u2f(v.w);
    }
  }
  ushort4 ev; ev.x=f2u(a0); ev.y=f2u(a1); ev.z=f2u(a2); ev.w=f2u(a3);
  *(ushort4*)(EF16 + (size_t)e*256 + lane*4) = ev;
}

// ---------------- per-node gather + residual + LayerNorm (pipelined) ----------------
__global__ __launch_bounds__(256) void k_node(const int* __restrict__ noff, const int* __restrict__ np,
    const int* __restrict__ eidx, const float* __restrict__ attn, const unsigned short* __restrict__ EF16,
    const float* __restrict__ lng, const float* __restrict__ lnb,
    bf16* __restrict__ h16, void* __restrict__ outv, const int* __restrict__ flag, int last){
  int n = blockIdx.x*4 + (threadIdx.x>>6);
  int lane = threadIdx.x & 63;
  if (n >= N_) return;
  float f0=0,f1=0,f2=0,f3=0;
  int beg = noff[n], end = noff[n+1];
  int deg = end - beg;
  if (deg > 0 && deg <= 64){
    int i = beg + lane;
    int e = 0;
    float4 w; w.x=w.y=w.z=w.w=0.f;
    if (lane < deg){
      int m = np[i]; e = eidx[m];
      w = *(const float4*)(attn + (size_t)m*4);
    }
    auto ldrow = [&](int j)->ushort4{
      int ee = __shfl(e, j, 64);
      return *(const ushort4*)(EF16 + (size_t)ee*256 + (lane<<2));
    };
    ushort4 v0v,v1v,v2v,v3v;
    if (deg>0) v0v=ldrow(0);
    if (deg>1) v1v=ldrow(1);
    if (deg>2) v2v=ldrow(2);
    if (deg>3) v3v=ldrow(3);
    for (int j=0;j<deg;j+=4){
      { float wx=__shfl(w.x,j,64),wy=__shfl(w.y,j,64),wz=__shfl(w.z,j,64),wq=__shfl(w.w,j,64);
        f0+=wx*u2f(v0v.x); f1+=wy*u2f(v0v.y); f2+=wz*u2f(v0v.z); f3+=wq*u2f(v0v.w);
        if (j+4<deg) v0v=ldrow(j+4); }
      if (j+1<deg){
        float wx=__shfl(w.x,j+1,64),wy=__shfl(w.y,j+1,64),wz=__shfl(w.z,j+1,64),wq=__shfl(w.w,j+1,64);
        f0+=wx*u2f(v1v.x); f1+=wy*u2f(v1v.y); f2+=wz*u2f(v1v.z); f3+=wq*u2f(v1v.w);
        if (j+5<deg) v1v=ldrow(j+5); }
      if (j+2<deg){
        float wx=__shfl(w.x,j+2,64),wy=__shfl(w.y,j+2,64),wz=__shfl(w.z,j+2,64),wq=__shfl(w.w,j+2,64);
        f0+=wx*u2f(v2v.x); f1+=wy*u2f(v2v.y); f2+=wz*u2f(v2v.z); f3+=wq*u2f(v2v.w);
        if (j+6<deg) v2v=ldrow(j+6); }
      if (j+3<deg){
        float wx=__shfl(w.x,j+3,64),wy=__shfl(w.y,j+3,64),wz=__shfl(w.z,j+3,64),wq=__shfl(w.w,j+3,64);
        f0+=wx*u2f(v3v.x); f1+=wy*u2f(v3v.y); f2+=wz*u2f(v3v.z); f3+=wq*u2f(v3v.w);
        if (j+7<deg) v3v=ldrow(j+7); }
    }
  } else if (deg > 64){
    for (int i=beg; i<end; ++i){
      int m = np[i]; int e = eidx[m];
      float4 w = *(const float4*)(attn + (size_t)m*4);
      ushort4 v = *(const ushort4*)(EF16 + (size_t)e*256 + lane*4);
      f0 += w.x*u2f(v.x); f1 += w.y*u2f(v.y); f2 += w.z*u2f(v.z); f3 += w.w*u2f(v.w);
    }
  }
  const bf16* hp = h16 + (size_t)n*256;
  float h0 = b2f(hp[lane])+f0, h1 = b2f(hp[64+lane])+f1, h2 = b2f(hp[128+lane])+f2, h3 = b2f(hp[192+lane])+f3;
  float s = h0+h1+h2+h3;
  #pragma unroll
  for (int d=1; d<64; d<<=1) s += __shfl_xor(s,d,64);
  float mean = s * (1.f/256.f);
  float d0=h0-mean, d1=h1-mean, d2=h2-mean, d3=h3-mean;
  float vv = d0*d0+d1*d1+d2*d2+d3*d3;
  #pragma unroll
  for (int d=1; d<64; d<<=1) vv += __shfl_xor(vv,d,64);
  float rstd = rsqrtf(vv*(1.f/256.f) + 1e-5f);
  float o0 = d0*rstd*lng[lane]     + lnb[lane];
  float o1 = d1*rstd*lng[64+lane]  + lnb[64+lane];
  float o2 = d2*rstd*lng[128+lane] + lnb[128+lane];
  float o3 = d3*rstd*lng[192+lane] + lnb[192+lane];
  if (last){
    if (*flag){
      bf16* op = (bf16*)outv + (size_t)n*256;
      op[lane]=__float2bfloat16(o0); op[64+lane]=__float2bfloat16(o1);
      op[128+lane]=__float2bfloat16(o2); op[192+lane]=__float2bfloat16(o3);
    } else {
      float* op = (float*)outv + (size_t)n*256;
      op[lane]=o0; op[64+lane]=o1; op[128+lane]=o2; op[192+lane]=o3;
    }
  } else {
    bf16* o16 = h16 + (size_t)n*256;
    o16[lane]=__float2bfloat16(o0); o16[64+lane]=__float2bfloat16(o1);
    o16[128+lane]=__float2bfloat16(o2); o16[192+lane]=__float2bfloat16(o3);
  }
}

extern "C" void kernel_launch(void* const* d_in, const int* in_sizes, int n_in,
                              void* d_out, int out_size, void* d_ws, size_t ws_size,
                              hipStream_t stream){
  const void* x    = d_in[0];
  const int* ntype = (const int*)d_in[1];
  const int* etype = (const int*)d_in[2];
  const int* nidx  = (const int*)d_in[3];
  const int* eidx  = (const int*)d_in[4];
  (void)in_sizes; (void)n_in; (void)out_size; (void)ws_size;

  char* ws = (char*)d_ws;
  size_t o = 0;
  auto alloc = [&](size_t b)->char*{ char* r = ws + o; o = (o + b + 255) & ~(size_t)255; return r; };
  int*   flag = (int*)  alloc(256);
  char*  R2   =         alloc((size_t)20000000);          // Hb16+S (gemm->gate) / attn+EF16 (edge->node)
  float* G    = (float*)alloc((size_t)N_*12*4);
  float* tq_f  = (float*)alloc(1536*4);
  float* w1_f  = (float*)alloc(81920*4);
  float* b1_f  = (float*)alloc(256*4);
  float* w2_f  = (float*)alloc(256*4);
  float* b2_f  = (float*)alloc(8*4);
  float* wq_f  = (float*)alloc(131072*4);
  float* wv_f  = (float*)alloc(131072*4);
  float* ec_f  = (float*)alloc(1536*4);
  float* lng_f = (float*)alloc(512*4);
  float* lnb_f = (float*)alloc(512*4);
  float* wqe   = (float*)alloc(6144*4);
  float* pre   = (float*)alloc(768*4);
  int* cnt_e  = (int*)alloc((size_t)E_*4);
  int* cnt_n  = (int*)alloc((size_t)N_*4);
  int* eoff   = (int*)alloc((size_t)(E_+1)*4);
  int* noff   = (int*)alloc((size_t)(N_+1)*4);
  int* cur_e  = (int*)alloc((size_t)E_*4);
  int* cur_n  = (int*)alloc((size_t)N_*4);
  int* ep     = (int*)alloc((size_t)M_*4);
  int* np     = (int*)alloc((size_t)M_*4);
  int* bsum_e = (int*)alloc(256*4);
  int* bsum_n = (int*)alloc(256*4);
  bf16* h16   = (bf16*)alloc((size_t)NPAD_*256*2);        // 25.6 MB bf16 hidden state (A for MFMA)
  bf16* Bp    = (bf16*)alloc((size_t)2*448*256*2);
  bf16* V16   = (bf16*)alloc((size_t)N_*256*2);           // 25.6 MB interleaved [n][d][h]

  bf16*  Hb16 = (bf16*)R2;                                 // 12.8 MB
  float* S    = (float*)(R2 + 16777216);                   // 2.4 MB
  float* attn = (float*)R2;                                // 5.12 MB
  unsigned short* EF16 = (unsigned short*)(R2 + 5242880);  // 10.24 MB (ends 15.48M < S)

  k_sniff<<<1, 256, 0, stream>>>((const unsigned short*)x, flag);
  k_cvt16<<<(N_*256+255)/256, 256, 0, stream>>>(x, h16, N_*256, flag);
  k_cvtall<<<(348936+255)/256, 256, 0, stream>>>(
      d_in[5], d_in[6], d_in[7], d_in[8], d_in[9],
      d_in[10], d_in[11], d_in[12], d_in[13], d_in[14],
      tq_f, w1_f, b1_f, w2_f, b2_f, wq_f, wv_f, ec_f, lng_f, lnb_f, flag);

  k_zero2<<<(E_+N_+255)/256, 256, 0, stream>>>(cnt_e, cnt_n);
  k_hist<<<M_/256, 256, 0, stream>>>(eidx, nidx, cnt_e, cnt_n);
  k_scan1m<<<NB_E+NB_N, 256, 0, stream>>>(cnt_e, eoff, bsum_e, cnt_n, noff, bsum_n);
  k_scan2m<<<2, 256, 0, stream>>>(bsum_e, eoff, bsum_n, noff);
  k_scan3m<<<NB_E+NB_N, 256, 0, stream>>>(bsum_e, eoff, cur_e, bsum_n, noff, cur_n);
  k_fill<<<M_/256, 256, 0, stream>>>(eidx, nidx, cur_e, cur_n, ep, np);
  k_pre<<<3, 256, 0, stream>>>(tq_f, w1_f, b1_f, pre);
  k_wqe<<<24, 256, 0, stream>>>(wq_f, ec_f, wqe);
  k_bpack<<<(2*448*256+255)/256, 256, 0, stream>>>(wv_f, w1_f, wqe, Bp);

  for (int l=0; l<2; ++l){
    k_mgemm<<<2744, 256, 0, stream>>>(h16, Bp + (size_t)l*448*256, V16, Hb16, S);
    k_gate<<<12500, 256, 0, stream>>>((const unsigned short*)Hb16, S, pre + l*384,
                                      w2_f + l*128, b2_f + l*4, ntype, G);
    k_edge<<<5000, 256, 0, stream>>>(eoff, ep, nidx, etype, G, (const unsigned short*)V16, attn, EF16);
    k_node<<<12500, 256, 0, stream>>>(noff, np, eidx, attn, EF16, lng_f + l*256, lnb_f + l*256,
                                      h16, d_out, flag, l==1);
  }
}

// Round 2
// 470.491 us; speedup vs baseline: 1.1624x; 1.1607x over previous
//
#include <hip/hip_runtime.h>
#include <hip/hip_bf16.h>

typedef __hip_bfloat16 bf16;
using short8  = __attribute__((ext_vector_type(8))) short;
using float4v = __attribute__((ext_vector_type(4))) float;

static constexpr int N_ = 50000;   // nodes
static constexpr int E_ = 20000;   // hyperedges
static constexpr int M_ = 320000;  // incidence pairs
static constexpr int NPAD_ = 50048;  // 391*128 rows for MFMA grid
static constexpr int NB_E = (E_+255)/256;   // 79
static constexpr int NB_N = (N_+255)/256;   // 196

__device__ __forceinline__ float b2f(bf16 v){ return __bfloat162float(v); }
__device__ __forceinline__ float sigm(float x){ return 1.f/(1.f+__expf(-x)); }
__device__ __forceinline__ float u2f(unsigned short u){ return __uint_as_float(((unsigned)u)<<16); }
__device__ __forceinline__ unsigned short f2u(float f){ bf16 t=__float2bfloat16(f); return *(unsigned short*)&t; }

// ---------------- dtype sniff ----------------
__global__ __launch_bounds__(256) void k_sniff(const unsigned short* __restrict__ xb, int* flag){
  int tid = threadIdx.x;
  int sane = 0;
  for (int i = tid; i < 4096; i += 256){
    unsigned short u = xb[2*i];
    int ex = (u >> 7) & 0xFF;
    if ((u & 0x7FFF) == 0 || (ex >= 117 && ex <= 137)) sane++;
  }
  #pragma unroll
  for (int d=1; d<64; d<<=1) sane += __shfl_xor(sane, d, 64);
  __shared__ int wsh[4];
  if ((tid&63)==0) wsh[tid>>6] = sane;
  __syncthreads();
  if (tid==0){
    int tot = wsh[0]+wsh[1]+wsh[2]+wsh[3];
    *flag = (tot > 2048) ? 1 : 0;    // 1 = bf16 storage
  }
}

// ---------------- converts ----------------
__global__ __launch_bounds__(256) void k_cvt16(const void* __restrict__ src, bf16* __restrict__ dst,
                                               int n, const int* __restrict__ flag){
  int i = blockIdx.x*256 + threadIdx.x;
  if (i >= n) return;
  if (*flag) dst[i] = ((const bf16*)src)[i];
  else       dst[i] = __float2bfloat16(((const float*)src)[i]);
}

// all 10 small weight tensors -> fp32, one launch
__global__ __launch_bounds__(256) void k_cvtall(
    const void* s0, const void* s1, const void* s2, const void* s3, const void* s4,
    const void* s5, const void* s6, const void* s7, const void* s8, const void* s9,
    float* d0, float* d1, float* d2, float* d3, float* d4,
    float* d5, float* d6, float* d7, float* d8, float* d9,
    const int* __restrict__ flag){
  int i = blockIdx.x*256 + threadIdx.x;
  const void* src; float* dst; int off;
  if      (i < 1536)            { src=s0; dst=d0; off=i; }
  else if (i < 1536+81920)      { src=s1; dst=d1; off=i-1536; }
  else if (i < 83712+256)       { src=s2; dst=d2; off=i-83712; }
  else if (i < 83968+256)       { src=s3; dst=d3; off=i-83968; }
  else if (i < 84224+8)         { src=s4; dst=d4; off=i-84224; }
  else if (i < 84232+131072)    { src=s5; dst=d5; off=i-84232; }
  else if (i < 215304+131072)   { src=s6; dst=d6; off=i-215304; }
  else if (i < 346376+1536)     { src=s7; dst=d7; off=i-346376; }
  else if (i < 347912+512)      { src=s8; dst=d8; off=i-347912; }
  else if (i < 348424+512)      { src=s9; dst=d9; off=i-348424; }
  else return;
  if (*flag) dst[off] = b2f(((const bf16*)src)[off]);
  else       dst[off] = ((const float*)src)[off];
}

__global__ __launch_bounds__(256) void k_zero2(int* pe, int* pn){
  int i = blockIdx.x*256 + threadIdx.x;
  if (i < E_) pe[i] = 0;
  else if (i < E_+N_) pn[i-E_] = 0;
}

// ---------------- CSR build ----------------
__global__ __launch_bounds__(256) void k_hist(const int* __restrict__ eidx, const int* __restrict__ nidx,
                                              int* cnt_e, int* cnt_n){
  int m = blockIdx.x*256 + threadIdx.x;
  if (m < M_){ atomicAdd(&cnt_e[eidx[m]],1); atomicAdd(&cnt_n[nidx[m]],1); }
}

__device__ __forceinline__ void scan1_body(const int* cnt, int* off, int* bsum, int n, int blk){
  int tid = threadIdx.x, lane = tid&63, wid = tid>>6;
  int i = blk*256 + tid;
  int v = (i<n)? cnt[i] : 0;
  int s = v;
  #pragma unroll
  for (int d=1; d<64; d<<=1){ int t = __shfl_up(s, d, 64); if (lane>=d) s += t; }
  __shared__ int ws[4]; __shared__ int wo[4];
  if (lane==63) ws[wid] = s;
  __syncthreads();
  if (tid==0){ int a=0; for (int k=0;k<4;k++){ int t=ws[k]; wo[k]=a; a+=t; } bsum[blk]=a; }
  __syncthreads();
  if (i<n) off[i] = wo[wid] + s - v;
}

__global__ __launch_bounds__(256) void k_scan1m(const int* __restrict__ cnt_e, int* __restrict__ eoff, int* bsum_e,
                                                const int* __restrict__ cnt_n, int* __restrict__ noff, int* bsum_n){
  int b = blockIdx.x;
  if (b < NB_E) scan1_body(cnt_e, eoff, bsum_e, E_, b);
  else          scan1_body(cnt_n, noff, bsum_n, N_, b-NB_E);
}

__device__ __forceinline__ void scan2_body(int* bsum, int* off, int nb, int n){
  int tid = threadIdx.x, lane = tid&63, wid = tid>>6;
  int v = (tid<nb)? bsum[tid] : 0;
  int s = v;
  #pragma unroll
  for (int d=1; d<64; d<<=1){ int t = __shfl_up(s, d, 64); if (lane>=d) s += t; }
  __shared__ int ws[4]; __shared__ int wo[4];
  if (lane==63) ws[wid] = s;
  __syncthreads();
  if (tid==0){ int a=0; for (int k=0;k<4;k++){ int t=ws[k]; wo[k]=a; a+=t; } off[n]=a; }
  __syncthreads();
  if (tid<nb) bsum[tid] = wo[wid] + s - v;
}

__global__ __launch_bounds__(256) void k_scan2m(int* bsum_e, int* __restrict__ eoff,
                                                int* bsum_n, int* __restrict__ noff){
  if (blockIdx.x == 0) scan2_body(bsum_e, eoff, NB_E, E_);
  else                 scan2_body(bsum_n, noff, NB_N, N_);
}

__global__ __launch_bounds__(256) void k_scan3m(const int* __restrict__ bsum_e, int* __restrict__ eoff, int* cur_e,
                                                const int* __restrict__ bsum_n, int* __restrict__ noff, int* cur_n){
  int b = blockIdx.x;
  if (b < NB_E){
    int i = b*256 + threadIdx.x;
    if (i<E_){ int e = eoff[i] + bsum_e[b]; eoff[i]=e; cur_e[i]=e; }
  } else {
    int i = (b-NB_E)*256 + threadIdx.x;
    if (i<N_){ int e = noff[i] + bsum_n[b-NB_E]; noff[i]=e; cur_n[i]=e; }
  }
}

__global__ __launch_bounds__(256) void k_fill(const int* __restrict__ eidx, const int* __restrict__ nidx,
                                              int* cur_e, int* cur_n, int* ep, int* np){
  int m = blockIdx.x*256 + threadIdx.x;
  if (m < M_){
    int p = atomicAdd(&cur_e[eidx[m]],1); ep[p]=m;
    int q = atomicAdd(&cur_n[nidx[m]],1); np[q]=m;
  }
}

// ---------------- pre / wqe / bpack ----------------
__global__ __launch_bounds__(256) void k_pre(const float* __restrict__ tq, const float* __restrict__ w1,
                                             const float* __restrict__ b1, float* __restrict__ pre){
  int idx = blockIdx.x*256 + threadIdx.x;
  if (idx >= 768) return;
  int l = idx / 384, r = idx % 384;
  int t = r / 128, r2 = r % 128;
  int h = r2 >> 5, k = r2 & 31;
  const float* tp = tq + ((l*4+h)*3 + t)*64;
  const float* wp = w1 + (size_t)((l*4+h)*32 + k)*320 + 256;
  float s = b1[(l*4+h)*32 + k];
  for (int d=0; d<64; ++d) s += tp[d]*wp[d];
  pre[(l*3+t)*128 + r2] = s;
}

__global__ __launch_bounds__(256) void k_wqe(const float* __restrict__ wq_f, const float* __restrict__ ec_f,
                                             float* __restrict__ wqe){
  int b = blockIdx.x;
  int l = b/12, ht = b%12, h = ht/3, t = ht%3;
  int d = threadIdx.x;
  const float* ecp = ec_f + ((l*4+h)*3 + t)*64;
  const float* wqp = wq_f + (size_t)((l*4+h)*64)*256;
  float s = 0.f;
  for (int o=0;o<64;++o) s += ecp[o]*wqp[o*256 + d];
  wqe[(size_t)(l*12+ht)*256 + d] = s;
}

// pack B panel with V cols PERMUTED to the V16 interleave order
__global__ __launch_bounds__(256) void k_bpack(const float* __restrict__ wv_f, const float* __restrict__ w1_f,
                                               const float* __restrict__ wqe, bf16* __restrict__ Bp){
  int idx = blockIdx.x*256 + threadIdx.x;
  if (idx >= 2*448*256) return;
  int l = idx / (448*256), r = idx % (448*256);
  int c = r >> 8, k = r & 255;
  float v = 0.f;
  if (c < 256){
    int dd = c >> 2, h = c & 3;
    v = wv_f[(size_t)l*65536 + (size_t)(h*64+dd)*256 + k];
  }
  else if (c < 384) v = w1_f[(size_t)l*40960 + (size_t)(c-256)*320 + k];
  else if (c < 396) v = wqe[(size_t)(l*12 + c-384)*256 + k];
  Bp[idx] = __float2bfloat16(v);
}

// ---------------- MFMA GEMM: LDS-staged (m97 structure), XOR-swizzled, counted vmcnt ----------------
// Theory fix vs prior rounds: direct per-lane fragment loads from global are 16-line
// gathers per instruction (row stride 512B) -> line-request throughput wall (~70us,
// invariant to pipelining). Here: global_load_lds stages A(128x64) + B(64x64) tiles
// (each staging instr = 8 rows x 128B contiguous = minimal line count), B shared by
// all 4 waves, double-buffered BK=64, counted vmcnt(6) keeps next-tile loads in
// flight across raw s_barriers. LDS granule swizzle g^=(row&7) applied on BOTH the
// global source (pre-swizzle) and the ds_read side -> ds_read_b128 ~conflict-free.
__global__ __launch_bounds__(256,3) void k_mgemm(const bf16* __restrict__ A16, const bf16* __restrict__ Bp,
    bf16* __restrict__ V16, bf16* __restrict__ Hb16, float* __restrict__ S){
  // bijective XCD swizzle (m204), nwg=2737=8*342+1; x fastest within an XCD -> A-panel L2 reuse
  int g = blockIdx.x;
  int xcd = g & 7, i7 = g >> 3;
  int wgid = (xcd==0) ? i7 : (343 + (xcd-1)*342 + i7);
  int x = wgid % 7, y = wgid / 7;

  int t = threadIdx.x;
  int wid = t >> 6, lane = t & 63;
  int q = lane >> 4, li = lane & 15;
  int row0blk = y*128;
  int col0 = x*64;
  int w32 = wid*32;

  __shared__ char lds[49152];   // [A0 16K][B0 8K][A1 16K][B1 8K]

  float4v acc[2][4];
  #pragma unroll
  for (int i=0;i<2;i++)
    #pragma unroll
    for (int j=0;j<4;j++) acc[i][j] = (float4v)(0.f);

  auto stage = [&](int st, int buf){
    const int k0 = st*64;
    char* lA = lds + (buf ? 24576 : 0);
    char* lB = lds + (buf ? 40960 : 16384);
    const bf16* Asrc = A16 + (size_t)row0blk*256 + k0;
    const bf16* Bsrc = Bp  + (size_t)col0*256 + k0;
    #pragma unroll
    for (int ra=0; ra<4; ++ra){
      int gidx = ra*256 + t;
      int r = gidx >> 3, c = gidx & 7;
      const bf16* src = Asrc + (size_t)r*256 + ((c ^ (r&7)) << 3);
      char* dst = lA + (ra*256 + wid*64)*16;   // wave-uniform base; HW adds lane*16
      __builtin_amdgcn_global_load_lds((const __attribute__((address_space(1))) void*)src,
                                       (__attribute__((address_space(3))) void*)dst, 16, 0, 0);
    }
    #pragma unroll
    for (int rb=0; rb<2; ++rb){
      int gidx = rb*256 + t;
      int r = gidx >> 3, c = gidx & 7;
      const bf16* src = Bsrc + (size_t)r*256 + ((c ^ (r&7)) << 3);
      char* dst = lB + (rb*256 + wid*64)*16;
      __builtin_amdgcn_global_load_lds((const __attribute__((address_space(1))) void*)src,
                                       (__attribute__((address_space(3))) void*)dst, 16, 0, 0);
    }
  };

  stage(0, 0);
  #pragma unroll
  for (int st=0; st<4; ++st){
    int bufc = st & 1;
    if (st < 3) stage(st+1, bufc^1);
    __builtin_amdgcn_sched_barrier(0);
    if (st < 3) asm volatile("s_waitcnt vmcnt(6)" ::: "memory");   // current tile done, next 6 in flight
    else        asm volatile("s_waitcnt vmcnt(0)" ::: "memory");
    __builtin_amdgcn_s_barrier();
    __builtin_amdgcn_sched_barrier(0);

    const char* cA = lds + (bufc ? 24576 : 0);
    const char* cB = lds + (bufc ? 40960 : 16384);
    short8 af[2][2], bfr[4][2];
    #pragma unroll
    for (int i=0;i<2;i++)
      #pragma unroll
      for (int k2=0;k2<2;k2++){
        int row = w32 + i*16 + li;
        int gr = (k2*4 + q) ^ (li & 7);
        af[i][k2] = *(const short8*)(cA + row*128 + gr*16);
      }
    #pragma unroll
    for (int j=0;j<4;j++)
      #pragma unroll
      for (int k2=0;k2<2;k2++){
        int row = j*16 + li;
        int gr = (k2*4 + q) ^ (li & 7);
        bfr[j][k2] = *(const short8*)(cB + row*128 + gr*16);
      }
    #pragma unroll
    for (int k2=0;k2<2;k2++)
      #pragma unroll
      for (int j=0;j<4;j++){
        acc[0][j] = __builtin_amdgcn_mfma_f32_16x16x32_bf16(af[0][k2], bfr[j][k2], acc[0][j],0,0,0);
        acc[1][j] = __builtin_amdgcn_mfma_f32_16x16x32_bf16(af[1][k2], bfr[j][k2], acc[1][j],0,0,0);
      }
    __builtin_amdgcn_sched_barrier(0);
    __builtin_amdgcn_s_barrier();
  }

  int row0 = row0blk + w32;
  #pragma unroll
  for (int i=0;i<2;i++){
    #pragma unroll
    for (int r=0;r<4;r++){
      int grow = row0 + i*16 + q*4 + r;
      if (grow >= N_) continue;
      #pragma unroll
      for (int j=0;j<4;j++){
        int gc = col0 + j*16 + li;
        float v = acc[i][j][r];
        if (gc < 256)      V16 [(size_t)grow*256 + gc]       = __float2bfloat16(v);  // contiguous (permuted)
        else if (gc < 384) Hb16[(size_t)grow*128 + gc - 256] = __float2bfloat16(v);
        else if (gc < 396) S   [(size_t)grow*12  + gc - 384] = v;
      }
    }
  }
}

// ---------------- per-node gate (Hb bf16) ----------------
__global__ __launch_bounds__(256) void k_gate(const unsigned short* __restrict__ Hb16, const float* __restrict__ S,
    const float* __restrict__ pre_l, const float* __restrict__ w2_l, const float* __restrict__ b2_l,
    const int* __restrict__ ntype, float* __restrict__ G){
  int node = blockIdx.x*4 + (threadIdx.x>>6);
  int lane = threadIdx.x & 63;
  if (node >= N_) return;
  int typ = ntype[node];
  const float* pr = pre_l + typ*128;
  float v0 = tanhf(u2f(Hb16[(size_t)node*128 + lane])      + pr[lane]);
  float v1 = tanhf(u2f(Hb16[(size_t)node*128 + 64 + lane]) + pr[64+lane]);
  float p0 = v0 * w2_l[lane];
  float p1 = v1 * w2_l[64+lane];
  #pragma unroll
  for (int d=1; d<32; d<<=1){ p0 += __shfl_xor(p0,d,64); p1 += __shfl_xor(p1,d,64); }
  float at0 = sigm(__shfl(p0, 0,64) + b2_l[0]);
  float at1 = sigm(__shfl(p0,32,64) + b2_l[1]);
  float at2 = sigm(__shfl(p1, 0,64) + b2_l[2]);
  float at3 = sigm(__shfl(p1,32,64) + b2_l[3]);
  if (lane < 12){
    int h = lane / 3, t = lane % 3;
    float sv = S[(size_t)node*12 + lane];
    float lr = (sv > 0.f) ? sv : 0.2f*sv;
    float av = (h==0)? at0 : (h==1)? at1 : (h==2)? at2 : at3;
    G[(size_t)node*12 + t*4 + h] = lr * av;
  }
}

// ---------------- per-edge softmax + edge_feat (single-pass, pipelined gather) ----------------
__global__ __launch_bounds__(256) void k_edge(const int* __restrict__ eoff, const int* __restrict__ ep,
    const int* __restrict__ nidx, const int* __restrict__ etype,
    const float* __restrict__ G, const unsigned short* __restrict__ V16,
    float* __restrict__ attn, unsigned short* __restrict__ EF16){
  int e = blockIdx.x*4 + (threadIdx.x>>6);
  int lane = threadIdx.x & 63;
  if (e >= E_) return;
  int beg = eoff[e], end = eoff[e+1];
  int deg = end - beg;
  if (deg == 0) return;
  int t = etype[e];
  float a0=0,a1=0,a2=0,a3=0;

  if (deg <= 64){
    int i = beg + lane;
    int m = -1, n = 0;
    float4 g; g.x=g.y=g.z=g.w=-1e30f;
    if (lane < deg){
      m = ep[i]; n = nidx[m];
      g = *(const float4*)(G + (size_t)n*12 + t*4);
    }
    float mx0=g.x, mx1=g.y, mx2=g.z, mx3=g.w;
    #pragma unroll
    for (int d=1; d<64; d<<=1){
      mx0=fmaxf(mx0,__shfl_xor(mx0,d,64)); mx1=fmaxf(mx1,__shfl_xor(mx1,d,64));
      mx2=fmaxf(mx2,__shfl_xor(mx2,d,64)); mx3=fmaxf(mx3,__shfl_xor(mx3,d,64));
    }
    float ex0=0,ex1=0,ex2=0,ex3=0;
    if (lane < deg){
      ex0=__expf(g.x-mx0); ex1=__expf(g.y-mx1); ex2=__expf(g.z-mx2); ex3=__expf(g.w-mx3);
    }
    float s0=ex0,s1=ex1,s2=ex2,s3=ex3;
    #pragma unroll
    for (int d=1; d<64; d<<=1){
      s0+=__shfl_xor(s0,d,64); s1+=__shfl_xor(s1,d,64);
      s2+=__shfl_xor(s2,d,64); s3+=__shfl_xor(s3,d,64);
    }
    float4 w; w.x=ex0/s0; w.y=ex1/s1; w.z=ex2/s2; w.w=ex3/s3;
    if (lane < deg) *(float4*)(attn + (size_t)m*4) = w;
    auto ldrow = [&](int j)->ushort4{
      int nn = __shfl(n, j, 64);
      return *(const ushort4*)(V16 + (size_t)nn*256 + (lane<<2));
    };
    ushort4 v0v,v1v,v2v,v3v;
    if (deg>0) v0v=ldrow(0);
    if (deg>1) v1v=ldrow(1);
    if (deg>2) v2v=ldrow(2);
    if (deg>3) v3v=ldrow(3);
    for (int j=0;j<deg;j+=4){
      { float wx=__shfl(w.x,j,64),wy=__shfl(w.y,j,64),wz=__shfl(w.z,j,64),wq=__shfl(w.w,j,64);
        a0+=wx*u2f(v0v.x); a1+=wy*u2f(v0v.y); a2+=wz*u2f(v0v.z); a3+=wq*u2f(v0v.w);
        if (j+4<deg) v0v=ldrow(j+4); }
      if (j+1<deg){
        float wx=__shfl(w.x,j+1,64),wy=__shfl(w.y,j+1,64),wz=__shfl(w.z,j+1,64),wq=__shfl(w.w,j+1,64);
        a0+=wx*u2f(v1v.x); a1+=wy*u2f(v1v.y); a2+=wz*u2f(v1v.z); a3+=wq*u2f(v1v.w);
        if (j+5<deg) v1v=ldrow(j+5); }
      if (j+2<deg){
        float wx=__shfl(w.x,j+2,64),wy=__shfl(w.y,j+2,64),wz=__shfl(w.z,j+2,64),wq=__shfl(w.w,j+2,64);
        a0+=wx*u2f(v2v.x); a1+=wy*u2f(v2v.y); a2+=wz*u2f(v2v.z); a3+=wq*u2f(v2v.w);
        if (j+6<deg) v2v=ldrow(j+6); }
      if (j+3<deg){
        float wx=__shfl(w.x,j+3,64),wy=__shfl(w.y,j+3,64),wz=__shfl(w.z,j+3,64),wq=__shfl(w.w,j+3,64);
        a0+=wx*u2f(v3v.x); a1+=wy*u2f(v3v.y); a2+=wz*u2f(v3v.z); a3+=wq*u2f(v3v.w);
        if (j+7<deg) v3v=ldrow(j+7); }
    }
  } else {
    float mx0=-1e30f, mx1=-1e30f, mx2=-1e30f, mx3=-1e30f;
    for (int i=beg+lane; i<end; i+=64){
      int m = ep[i]; int n = nidx[m];
      float4 g = *(const float4*)(G + (size_t)n*12 + t*4);
      mx0=fmaxf(mx0,g.x); mx1=fmaxf(mx1,g.y); mx2=fmaxf(mx2,g.z); mx3=fmaxf(mx3,g.w);
    }
    #pragma unroll
    for (int d=1; d<64; d<<=1){
      mx0=fmaxf(mx0,__shfl_xor(mx0,d,64)); mx1=fmaxf(mx1,__shfl_xor(mx1,d,64));
      mx2=fmaxf(mx2,__shfl_xor(mx2,d,64)); mx3=fmaxf(mx3,__shfl_xor(mx3,d,64));
    }
    float sm0=0,sm1=0,sm2=0,sm3=0;
    for (int i=beg+lane; i<end; i+=64){
      int m = ep[i]; int n = nidx[m];
      float4 g = *(const float4*)(G + (size_t)n*12 + t*4);
      sm0+=__expf(g.x-mx0); sm1+=__expf(g.y-mx1); sm2+=__expf(g.z-mx2); sm3+=__expf(g.w-mx3);
    }
    #pragma unroll
    for (int d=1; d<64; d<<=1){
      sm0+=__shfl_xor(sm0,d,64); sm1+=__shfl_xor(sm1,d,64);
      sm2+=__shfl_xor(sm2,d,64); sm3+=__shfl_xor(sm3,d,64);
    }
    float inv0=1.f/sm0, inv1=1.f/sm1, inv2=1.f/sm2, inv3=1.f/sm3;
    for (int i=beg+lane; i<end; i+=64){
      int m = ep[i]; int n = nidx[m];
      float4 g = *(const float4*)(G + (size_t)n*12 + t*4);
      float4 w;
      w.x=__expf(g.x-mx0)*inv0; w.y=__expf(g.y-mx1)*inv1;
      w.z=__expf(g.z-mx2)*inv2; w.w=__expf(g.w-mx3)*inv3;
      *(float4*)(attn + (size_t)m*4) = w;
    }
    for (int i=beg; i<end; ++i){
      int m = ep[i]; int n = nidx[m];
      float4 g = *(const float4*)(G + (size_t)n*12 + t*4);
      float w0=__expf(g.x-mx0)*inv0, w1=__expf(g.y-mx1)*inv1;
      float w2=__expf(g.z-mx2)*inv2, w3=__expf(g.w-mx3)*inv3;
      ushort4 v = *(const ushort4*)(V16 + (size_t)n*256 + lane*4);
      a0 += w0*u2f(v.x); a1 += w1*u2f(v.y); a2 += w2*u2f(v.z); a3 += w3*u2f(v.w);
    }
  }
  ushort4 ev; ev.x=f2u(a0); ev.y=f2u(a1); ev.z=f2u(a2); ev.w=f2u(a3);
  *(ushort4*)(EF16 + (size_t)e*256 + lane*4) = ev;
}

// ---------------- per-node gather + residual + LayerNorm (pipelined) ----------------
__global__ __launch_bounds__(256) void k_node(const int* __restrict__ noff, const int* __restrict__ np,
    const int* __restrict__ eidx, const float* __restrict__ attn, const unsigned short* __restrict__ EF16,
    const float* __restrict__ lng, const float* __restrict__ lnb,
    bf16* __restrict__ h16, void* __restrict__ outv, const int* __restrict__ flag, int last){
  int n = blockIdx.x*4 + (threadIdx.x>>6);
  int lane = threadIdx.x & 63;
  if (n >= N_) return;
  float f0=0,f1=0,f2=0,f3=0;
  int beg = noff[n], end = noff[n+1];
  int deg = end - beg;
  if (deg > 0 && deg <= 64){
    int i = beg + lane;
    int e = 0;
    float4 w; w.x=w.y=w.z=w.w=0.f;
    if (lane < deg){
      int m = np[i]; e = eidx[m];
      w = *(const float4*)(attn + (size_t)m*4);
    }
    auto ldrow = [&](int j)->ushort4{
      int ee = __shfl(e, j, 64);
      return *(const ushort4*)(EF16 + (size_t)ee*256 + (lane<<2));
    };
    ushort4 v0v,v1v,v2v,v3v;
    if (deg>0) v0v=ldrow(0);
    if (deg>1) v1v=ldrow(1);
    if (deg>2) v2v=ldrow(2);
    if (deg>3) v3v=ldrow(3);
    for (int j=0;j<deg;j+=4){
      { float wx=__shfl(w.x,j,64),wy=__shfl(w.y,j,64),wz=__shfl(w.z,j,64),wq=__shfl(w.w,j,64);
        f0+=wx*u2f(v0v.x); f1+=wy*u2f(v0v.y); f2+=wz*u2f(v0v.z); f3+=wq*u2f(v0v.w);
        if (j+4<deg) v0v=ldrow(j+4); }
      if (j+1<deg){
        float wx=__shfl(w.x,j+1,64),wy=__shfl(w.y,j+1,64),wz=__shfl(w.z,j+1,64),wq=__shfl(w.w,j+1,64);
        f0+=wx*u2f(v1v.x); f1+=wy*u2f(v1v.y); f2+=wz*u2f(v1v.z); f3+=wq*u2f(v1v.w);
        if (j+5<deg) v1v=ldrow(j+5); }
      if (j+2<deg){
        float wx=__shfl(w.x,j+2,64),wy=__shfl(w.y,j+2,64),wz=__shfl(w.z,j+2,64),wq=__shfl(w.w,j+2,64);
        f0+=wx*u2f(v2v.x); f1+=wy*u2f(v2v.y); f2+=wz*u2f(v2v.z); f3+=wq*u2f(v2v.w);
        if (j+6<deg) v2v=ldrow(j+6); }
      if (j+3<deg){
        float wx=__shfl(w.x,j+3,64),wy=__shfl(w.y,j+3,64),wz=__shfl(w.z,j+3,64),wq=__shfl(w.w,j+3,64);
        f0+=wx*u2f(v3v.x); f1+=wy*u2f(v3v.y); f2+=wz*u2f(v3v.z); f3+=wq*u2f(v3v.w);
        if (j+7<deg) v3v=ldrow(j+7); }
    }
  } else if (deg > 64){
    for (int i=beg; i<end; ++i){
      int m = np[i]; int e = eidx[m];
      float4 w = *(const float4*)(attn + (size_t)m*4);
      ushort4 v = *(const ushort4*)(EF16 + (size_t)e*256 + lane*4);
      f0 += w.x*u2f(v.x); f1 += w.y*u2f(v.y); f2 += w.z*u2f(v.z); f3 += w.w*u2f(v.w);
    }
  }
  const bf16* hp = h16 + (size_t)n*256;
  float h0 = b2f(hp[lane])+f0, h1 = b2f(hp[64+lane])+f1, h2 = b2f(hp[128+lane])+f2, h3 = b2f(hp[192+lane])+f3;
  float s = h0+h1+h2+h3;
  #pragma unroll
  for (int d=1; d<64; d<<=1) s += __shfl_xor(s,d,64);
  float mean = s * (1.f/256.f);
  float d0=h0-mean, d1=h1-mean, d2=h2-mean, d3=h3-mean;
  float vv = d0*d0+d1*d1+d2*d2+d3*d3;
  #pragma unroll
  for (int d=1; d<64; d<<=1) vv += __shfl_xor(vv,d,64);
  float rstd = rsqrtf(vv*(1.f/256.f) + 1e-5f);
  float o0 = d0*rstd*lng[lane]     + lnb[lane];
  float o1 = d1*rstd*lng[64+lane]  + lnb[64+lane];
  float o2 = d2*rstd*lng[128+lane] + lnb[128+lane];
  float o3 = d3*rstd*lng[192+lane] + lnb[192+lane];
  if (last){
    if (*flag){
      bf16* op = (bf16*)outv + (size_t)n*256;
      op[lane]=__float2bfloat16(o0); op[64+lane]=__float2bfloat16(o1);
      op[128+lane]=__float2bfloat16(o2); op[192+lane]=__float2bfloat16(o3);
    } else {
      float* op = (float*)outv + (size_t)n*256;
      op[lane]=o0; op[64+lane]=o1; op[128+lane]=o2; op[192+lane]=o3;
    }
  } else {
    bf16* o16 = h16 + (size_t)n*256;
    o16[lane]=__float2bfloat16(o0); o16[64+lane]=__float2bfloat16(o1);
    o16[128+lane]=__float2bfloat16(o2); o16[192+lane]=__float2bfloat16(o3);
  }
}

extern "C" void kernel_launch(void* const* d_in, const int* in_sizes, int n_in,
                              void* d_out, int out_size, void* d_ws, size_t ws_size,
                              hipStream_t stream){
  const void* x    = d_in[0];
  const int* ntype = (const int*)d_in[1];
  const int* etype = (const int*)d_in[2];
  const int* nidx  = (const int*)d_in[3];
  const int* eidx  = (const int*)d_in[4];
  (void)in_sizes; (void)n_in; (void)out_size; (void)ws_size;

  char* ws = (char*)d_ws;
  size_t o = 0;
  auto alloc = [&](size_t b)->char*{ char* r = ws + o; o = (o + b + 255) & ~(size_t)255; return r; };
  int*   flag = (int*)  alloc(256);
  char*  R2   =         alloc((size_t)20000000);          // Hb16+S (gemm->gate) / attn+EF16 (edge->node)
  float* G    = (float*)alloc((size_t)N_*12*4);
  float* tq_f  = (float*)alloc(1536*4);
  float* w1_f  = (float*)alloc(81920*4);
  float* b1_f  = (float*)alloc(256*4);
  float* w2_f  = (float*)alloc(256*4);
  float* b2_f  = (float*)alloc(8*4);
  float* wq_f  = (float*)alloc(131072*4);
  float* wv_f  = (float*)alloc(131072*4);
  float* ec_f  = (float*)alloc(1536*4);
  float* lng_f = (float*)alloc(512*4);
  float* lnb_f = (float*)alloc(512*4);
  float* wqe   = (float*)alloc(6144*4);
  float* pre   = (float*)alloc(768*4);
  int* cnt_e  = (int*)alloc((size_t)E_*4);
  int* cnt_n  = (int*)alloc((size_t)N_*4);
  int* eoff   = (int*)alloc((size_t)(E_+1)*4);
  int* noff   = (int*)alloc((size_t)(N_+1)*4);
  int* cur_e  = (int*)alloc((size_t)E_*4);
  int* cur_n  = (int*)alloc((size_t)N_*4);
  int* ep     = (int*)alloc((size_t)M_*4);
  int* np     = (int*)alloc((size_t)M_*4);
  int* bsum_e = (int*)alloc(256*4);
  int* bsum_n = (int*)alloc(256*4);
  bf16* h16   = (bf16*)alloc((size_t)NPAD_*256*2);        // 25.6 MB bf16 hidden state (A for MFMA)
  bf16* Bp    = (bf16*)alloc((size_t)2*448*256*2);
  bf16* V16   = (bf16*)alloc((size_t)N_*256*2);           // 25.6 MB interleaved [n][d][h]

  bf16*  Hb16 = (bf16*)R2;                                 // 12.8 MB
  float* S    = (float*)(R2 + 16777216);                   // 2.4 MB
  float* attn = (float*)R2;                                // 5.12 MB
  unsigned short* EF16 = (unsigned short*)(R2 + 5242880);  // 10.24 MB (ends 15.48M < S)

  k_sniff<<<1, 256, 0, stream>>>((const unsigned short*)x, flag);
  k_cvt16<<<(N_*256+255)/256, 256, 0, stream>>>(x, h16, N_*256, flag);
  k_cvtall<<<(348936+255)/256, 256, 0, stream>>>(
      d_in[5], d_in[6], d_in[7], d_in[8], d_in[9],
      d_in[10], d_in[11], d_in[12], d_in[13], d_in[14],
      tq_f, w1_f, b1_f, w2_f, b2_f, wq_f, wv_f, ec_f, lng_f, lnb_f, flag);

  k_zero2<<<(E_+N_+255)/256, 256, 0, stream>>>(cnt_e, cnt_n);
  k_hist<<<M_/256, 256, 0, stream>>>(eidx, nidx, cnt_e, cnt_n);
  k_scan1m<<<NB_E+NB_N, 256, 0, stream>>>(cnt_e, eoff, bsum_e, cnt_n, noff, bsum_n);
  k_scan2m<<<2, 256, 0, stream>>>(bsum_e, eoff, bsum_n, noff);
  k_scan3m<<<NB_E+NB_N, 256, 0, stream>>>(bsum_e, eoff, cur_e, bsum_n, noff, cur_n);
  k_fill<<<M_/256, 256, 0, stream>>>(eidx, nidx, cur_e, cur_n, ep, np);
  k_pre<<<3, 256, 0, stream>>>(tq_f, w1_f, b1_f, pre);
  k_wqe<<<24, 256, 0, stream>>>(wq_f, ec_f, wqe);
  k_bpack<<<(2*448*256+255)/256, 256, 0, stream>>>(wv_f, w1_f, wqe, Bp);

  for (int l=0; l<2; ++l){
    k_mgemm<<<2737, 256, 0, stream>>>(h16, Bp + (size_t)l*448*256, V16, Hb16, S);
    k_gate<<<12500, 256, 0, stream>>>((const unsigned short*)Hb16, S, pre + l*384,
                                      w2_f + l*128, b2_f + l*4, ntype, G);
    k_edge<<<5000, 256, 0, stream>>>(eoff, ep, nidx, etype, G, (const unsigned short*)V16, attn, EF16);
    k_node<<<12500, 256, 0, stream>>>(noff, np, eidx, attn, EF16, lng_f + l*256, lnb_f + l*256,
                                      h16, d_out, flag, l==1);
  }
}

// Round 3
// 459.994 us; speedup vs baseline: 1.1890x; 1.0228x over previous
//
#include <hip/hip_runtime.h>
#include <hip/hip_bf16.h>

typedef __hip_bfloat16 bf16;
using short8  = __attribute__((ext_vector_type(8))) short;
using float4v = __attribute__((ext_vector_type(4))) float;

static constexpr int N_ = 50000;   // nodes
static constexpr int E_ = 20000;   // hyperedges
static constexpr int M_ = 320000;  // incidence pairs
static constexpr int NPAD_ = 50048;  // 391*128 rows for MFMA grid
static constexpr int NB_E = (E_+255)/256;   // 79
static constexpr int NB_N = (N_+255)/256;   // 196

__device__ __forceinline__ float b2f(bf16 v){ return __bfloat162float(v); }
__device__ __forceinline__ float sigm(float x){ return 1.f/(1.f+__expf(-x)); }
__device__ __forceinline__ float u2f(unsigned short u){ return __uint_as_float(((unsigned)u)<<16); }
__device__ __forceinline__ unsigned short f2u(float f){ bf16 t=__float2bfloat16(f); return *(unsigned short*)&t; }

// ---------------- sniff + zero counters (launch 1) ----------------
__global__ __launch_bounds__(256) void k_sniffzero(const unsigned short* __restrict__ xb, int* flag,
                                                   int* cnt_e, int* cnt_n){
  int b = blockIdx.x, tid = threadIdx.x;
  if (b == 0){
    int sane = 0;
    for (int i = tid; i < 4096; i += 256){
      unsigned short u = xb[2*i];
      int ex = (u >> 7) & 0xFF;
      if ((u & 0x7FFF) == 0 || (ex >= 117 && ex <= 137)) sane++;
    }
    #pragma unroll
    for (int d=1; d<64; d<<=1) sane += __shfl_xor(sane, d, 64);
    __shared__ int wsh[4];
    if ((tid&63)==0) wsh[tid>>6] = sane;
    __syncthreads();
    if (tid==0){
      int tot = wsh[0]+wsh[1]+wsh[2]+wsh[3];
      *flag = (tot > 2048) ? 1 : 0;    // 1 = bf16 storage
    }
  } else {
    int i = (b-1)*256 + tid;
    if (i < E_) cnt_e[i] = 0;
    else if (i < E_+N_) cnt_n[i-E_] = 0;
  }
}

// ---------------- prep: cvt16 + cvtall + hist in one launch (launch 2) ----------------
// ranges: [0,50000) cvt16, [50000,51364) cvtall, [51364,52614) hist
__global__ __launch_bounds__(256) void k_prep(
    const void* __restrict__ x, bf16* __restrict__ h16,
    const void* s0, const void* s1, const void* s2, const void* s3, const void* s4,
    const void* s5, const void* s6, const void* s7, const void* s8, const void* s9,
    float* d0, float* d1, float* d2, float* d3, float* d4,
    float* d5, float* d6, float* d7, float* d8, float* d9,
    const int* __restrict__ eidx, const int* __restrict__ nidx,
    int* cnt_e, int* cnt_n,
    const int* __restrict__ flag){
  int b = blockIdx.x, t = threadIdx.x;
  if (b < 50000){
    int i = b*256 + t;       // 50000*256 == N_*256 exactly
    if (*flag) h16[i] = ((const bf16*)x)[i];
    else       h16[i] = __float2bfloat16(((const float*)x)[i]);
    return;
  }
  if (b < 51364){
    int i = (b-50000)*256 + t;
    const void* src; float* dst; int off;
    if      (i < 1536)            { src=s0; dst=d0; off=i; }
    else if (i < 1536+81920)      { src=s1; dst=d1; off=i-1536; }
    else if (i < 83712+256)       { src=s2; dst=d2; off=i-83712; }
    else if (i < 83968+256)       { src=s3; dst=d3; off=i-83968; }
    else if (i < 84224+8)         { src=s4; dst=d4; off=i-84224; }
    else if (i < 84232+131072)    { src=s5; dst=d5; off=i-84232; }
    else if (i < 215304+131072)   { src=s6; dst=d6; off=i-215304; }
    else if (i < 346376+1536)     { src=s7; dst=d7; off=i-346376; }
    else if (i < 347912+512)      { src=s8; dst=d8; off=i-347912; }
    else if (i < 348424+512)      { src=s9; dst=d9; off=i-348424; }
    else return;
    if (*flag) dst[off] = b2f(((const bf16*)src)[off]);
    else       dst[off] = ((const float*)src)[off];
    return;
  }
  int m = (b-51364)*256 + t;
  if (m < M_){ atomicAdd(&cnt_e[eidx[m]],1); atomicAdd(&cnt_n[nidx[m]],1); }
}

// ---------------- scan phase 1 ----------------
__device__ __forceinline__ void scan1_body(const int* cnt, int* off, int* bsum, int n, int blk){
  int tid = threadIdx.x, lane = tid&63, wid = tid>>6;
  int i = blk*256 + tid;
  int v = (i<n)? cnt[i] : 0;
  int s = v;
  #pragma unroll
  for (int d=1; d<64; d<<=1){ int t = __shfl_up(s, d, 64); if (lane>=d) s += t; }
  __shared__ int ws[4]; __shared__ int wo[4];
  if (lane==63) ws[wid] = s;
  __syncthreads();
  if (tid==0){ int a=0; for (int k=0;k<4;k++){ int t=ws[k]; wo[k]=a; a+=t; } bsum[blk]=a; }
  __syncthreads();
  if (i<n) off[i] = wo[wid] + s - v;
}

// scan1 + pre + bpack(with inline wqe) in one launch (launch 3)
// ranges: [0,275) scans, [275,278) pre, [278,1174) bpack
__global__ __launch_bounds__(256) void k_scan1w(
    const int* __restrict__ cnt_e, int* __restrict__ eoff, int* bsum_e,
    const int* __restrict__ cnt_n, int* __restrict__ noff, int* bsum_n,
    const float* __restrict__ tq_f, const float* __restrict__ w1_f, const float* __restrict__ b1_f,
    float* __restrict__ pre,
    const float* __restrict__ wv_f, const float* __restrict__ wq_f, const float* __restrict__ ec_f,
    bf16* __restrict__ Bp){
  int b = blockIdx.x;
  if (b < NB_E){ scan1_body(cnt_e, eoff, bsum_e, E_, b); return; }
  if (b < NB_E+NB_N){ scan1_body(cnt_n, noff, bsum_n, N_, b-NB_E); return; }
  int b2 = b - (NB_E+NB_N);
  if (b2 < 3){
    int idx = b2*256 + threadIdx.x;
    if (idx >= 768) return;
    int l = idx / 384, r = idx % 384;
    int t = r / 128, r2 = r % 128;
    int h = r2 >> 5, k = r2 & 31;
    const float* tp = tq_f + ((l*4+h)*3 + t)*64;
    const float* wp = w1_f + (size_t)((l*4+h)*32 + k)*320 + 256;
    float s = b1_f[(l*4+h)*32 + k];
    for (int d=0; d<64; ++d) s += tp[d]*wp[d];
    pre[(l*3+t)*128 + r2] = s;
    return;
  }
  int idx = (b2-3)*256 + threadIdx.x;
  if (idx >= 2*448*256) return;
  int l = idx / (448*256), r = idx % (448*256);
  int c = r >> 8, k = r & 255;
  float v = 0.f;
  if (c < 256){
    int dd = c >> 2, h = c & 3;
    v = wv_f[(size_t)l*65536 + (size_t)(h*64+dd)*256 + k];
  }
  else if (c < 384) v = w1_f[(size_t)l*40960 + (size_t)(c-256)*320 + k];
  else if (c < 396){
    int ht = c-384, h = ht/3, tt = ht%3;       // inline wqe dot (was k_wqe)
    const float* ecp = ec_f + ((l*4+h)*3 + tt)*64;
    const float* wqp = wq_f + (size_t)((l*4+h)*64)*256 + k;
    float s = 0.f;
    for (int o2=0; o2<64; ++o2) s += ecp[o2]*wqp[(size_t)o2*256];
    v = s;
  }
  Bp[idx] = __float2bfloat16(v);
}

// ---------------- scan phases 2+3 merged (launch 4): each block redundantly reduces block-sums ----------------
__global__ __launch_bounds__(256) void k_scan23(const int* __restrict__ bsum_e, int* __restrict__ eoff, int* cur_e,
                                                const int* __restrict__ bsum_n, int* __restrict__ noff, int* cur_n){
  int b = blockIdx.x, t = threadIdx.x, lane = t&63, wid = t>>6;
  int nb, n, blk;
  const int* bsum; int* off; int* cur;
  if (b < NB_E){ nb=NB_E; n=E_; bsum=bsum_e; off=eoff; cur=cur_e; blk=b; }
  else         { nb=NB_N; n=N_; bsum=bsum_n; off=noff; cur=cur_n; blk=b-NB_E; }
  int v = (t < blk) ? bsum[t] : 0;   // blk <= 195 < 256
  #pragma unroll
  for (int d=1; d<64; d<<=1) v += __shfl_xor(v, d, 64);
  __shared__ int ws[4];
  if (lane==0) ws[wid] = v;
  __syncthreads();
  int p = ws[0]+ws[1]+ws[2]+ws[3];
  int i = blk*256 + t;
  if (i < n){ int e = off[i] + p; off[i] = e; cur[i] = e; }
  if (blk == nb-1 && t == 0) off[n] = p + bsum[nb-1];
}

__global__ __launch_bounds__(256) void k_fill(const int* __restrict__ eidx, const int* __restrict__ nidx,
                                              int* cur_e, int* cur_n, int* ep, int* np){
  int m = blockIdx.x*256 + threadIdx.x;
  if (m < M_){
    int p = atomicAdd(&cur_e[eidx[m]],1); ep[p]=m;
    int q = atomicAdd(&cur_n[nidx[m]],1); np[q]=m;
  }
}

// ---------------- MFMA GEMM: LDS-staged, XOR-swizzled, counted vmcnt ----------------
__global__ __launch_bounds__(256,3) void k_mgemm(const bf16* __restrict__ A16, const bf16* __restrict__ Bp,
    bf16* __restrict__ V16, bf16* __restrict__ Hb16, float* __restrict__ S){
  // bijective XCD swizzle (m204), nwg=2737=8*342+1; x fastest within an XCD -> A-panel L2 reuse
  int g = blockIdx.x;
  int xcd = g & 7, i7 = g >> 3;
  int wgid = (xcd==0) ? i7 : (343 + (xcd-1)*342 + i7);
  int x = wgid % 7, y = wgid / 7;

  int t = threadIdx.x;
  int wid = t >> 6, lane = t & 63;
  int q = lane >> 4, li = lane & 15;
  int row0blk = y*128;
  int col0 = x*64;
  int w32 = wid*32;

  __shared__ char lds[49152];   // [A0 16K][B0 8K][A1 16K][B1 8K]

  float4v acc[2][4];
  #pragma unroll
  for (int i=0;i<2;i++)
    #pragma unroll
    for (int j=0;j<4;j++) acc[i][j] = (float4v)(0.f);

  auto stage = [&](int st, int buf){
    const int k0 = st*64;
    char* lA = lds + (buf ? 24576 : 0);
    char* lB = lds + (buf ? 40960 : 16384);
    const bf16* Asrc = A16 + (size_t)row0blk*256 + k0;
    const bf16* Bsrc = Bp  + (size_t)col0*256 + k0;
    #pragma unroll
    for (int ra=0; ra<4; ++ra){
      int gidx = ra*256 + t;
      int r = gidx >> 3, c = gidx & 7;
      const bf16* src = Asrc + (size_t)r*256 + ((c ^ (r&7)) << 3);
      char* dst = lA + (ra*256 + wid*64)*16;   // wave-uniform base; HW adds lane*16
      __builtin_amdgcn_global_load_lds((const __attribute__((address_space(1))) void*)src,
                                       (__attribute__((address_space(3))) void*)dst, 16, 0, 0);
    }
    #pragma unroll
    for (int rb=0; rb<2; ++rb){
      int gidx = rb*256 + t;
      int r = gidx >> 3, c = gidx & 7;
      const bf16* src = Bsrc + (size_t)r*256 + ((c ^ (r&7)) << 3);
      char* dst = lB + (rb*256 + wid*64)*16;
      __builtin_amdgcn_global_load_lds((const __attribute__((address_space(1))) void*)src,
                                       (__attribute__((address_space(3))) void*)dst, 16, 0, 0);
    }
  };

  stage(0, 0);
  #pragma unroll
  for (int st=0; st<4; ++st){
    int bufc = st & 1;
    if (st < 3) stage(st+1, bufc^1);
    __builtin_amdgcn_sched_barrier(0);
    if (st < 3) asm volatile("s_waitcnt vmcnt(6)" ::: "memory");   // current tile done, next 6 in flight
    else        asm volatile("s_waitcnt vmcnt(0)" ::: "memory");
    __builtin_amdgcn_s_barrier();
    __builtin_amdgcn_sched_barrier(0);

    const char* cA = lds + (bufc ? 24576 : 0);
    const char* cB = lds + (bufc ? 40960 : 16384);
    short8 af[2][2], bfr[4][2];
    #pragma unroll
    for (int i=0;i<2;i++)
      #pragma unroll
      for (int k2=0;k2<2;k2++){
        int row = w32 + i*16 + li;
        int gr = (k2*4 + q) ^ (li & 7);
        af[i][k2] = *(const short8*)(cA + row*128 + gr*16);
      }
    #pragma unroll
    for (int j=0;j<4;j++)
      #pragma unroll
      for (int k2=0;k2<2;k2++){
        int row = j*16 + li;
        int gr = (k2*4 + q) ^ (li & 7);
        bfr[j][k2] = *(const short8*)(cB + row*128 + gr*16);
      }
    #pragma unroll
    for (int k2=0;k2<2;k2++)
      #pragma unroll
      for (int j=0;j<4;j++){
        acc[0][j] = __builtin_amdgcn_mfma_f32_16x16x32_bf16(af[0][k2], bfr[j][k2], acc[0][j],0,0,0);
        acc[1][j] = __builtin_amdgcn_mfma_f32_16x16x32_bf16(af[1][k2], bfr[j][k2], acc[1][j],0,0,0);
      }
    __builtin_amdgcn_sched_barrier(0);
    __builtin_amdgcn_s_barrier();
  }

  int row0 = row0blk + w32;
  #pragma unroll
  for (int i=0;i<2;i++){
    #pragma unroll
    for (int r=0;r<4;r++){
      int grow = row0 + i*16 + q*4 + r;
      if (grow >= N_) continue;
      #pragma unroll
      for (int j=0;j<4;j++){
        int gc = col0 + j*16 + li;
        float v = acc[i][j][r];
        if (gc < 256)      V16 [(size_t)grow*256 + gc]       = __float2bfloat16(v);  // contiguous (permuted)
        else if (gc < 384) Hb16[(size_t)grow*128 + gc - 256] = __float2bfloat16(v);
        else if (gc < 396) S   [(size_t)grow*12  + gc - 384] = v;
      }
    }
  }
}

// ---------------- per-node gate (Hb bf16) ----------------
__global__ __launch_bounds__(256) void k_gate(const unsigned short* __restrict__ Hb16, const float* __restrict__ S,
    const float* __restrict__ pre_l, const float* __restrict__ w2_l, const float* __restrict__ b2_l,
    const int* __restrict__ ntype, float* __restrict__ G){
  int node = blockIdx.x*4 + (threadIdx.x>>6);
  int lane = threadIdx.x & 63;
  if (node >= N_) return;
  int typ = ntype[node];
  const float* pr = pre_l + typ*128;
  float v0 = tanhf(u2f(Hb16[(size_t)node*128 + lane])      + pr[lane]);
  float v1 = tanhf(u2f(Hb16[(size_t)node*128 + 64 + lane]) + pr[64+lane]);
  float p0 = v0 * w2_l[lane];
  float p1 = v1 * w2_l[64+lane];
  #pragma unroll
  for (int d=1; d<32; d<<=1){ p0 += __shfl_xor(p0,d,64); p1 += __shfl_xor(p1,d,64); }
  float at0 = sigm(__shfl(p0, 0,64) + b2_l[0]);
  float at1 = sigm(__shfl(p0,32,64) + b2_l[1]);
  float at2 = sigm(__shfl(p1, 0,64) + b2_l[2]);
  float at3 = sigm(__shfl(p1,32,64) + b2_l[3]);
  if (lane < 12){
    int h = lane / 3, t = lane % 3;
    float sv = S[(size_t)node*12 + lane];
    float lr = (sv > 0.f) ? sv : 0.2f*sv;
    float av = (h==0)? at0 : (h==1)? at1 : (h==2)? at2 : at3;
    G[(size_t)node*12 + t*4 + h] = lr * av;
  }
}

// ---------------- per-edge softmax + edge_feat (single-pass, pipelined gather) ----------------
__global__ __launch_bounds__(256) void k_edge(const int* __restrict__ eoff, const int* __restrict__ ep,
    const int* __restrict__ nidx, const int* __restrict__ etype,
    const float* __restrict__ G, const unsigned short* __restrict__ V16,
    float* __restrict__ attn, unsigned short* __restrict__ EF16){
  int e = blockIdx.x*4 + (threadIdx.x>>6);
  int lane = threadIdx.x & 63;
  if (e >= E_) return;
  int beg = eoff[e], end = eoff[e+1];
  int deg = end - beg;
  if (deg == 0) return;
  int t = etype[e];
  float a0=0,a1=0,a2=0,a3=0;

  if (deg <= 64){
    int i = beg + lane;
    int m = -1, n = 0;
    float4 g; g.x=g.y=g.z=g.w=-1e30f;
    if (lane < deg){
      m = ep[i]; n = nidx[m];
      g = *(const float4*)(G + (size_t)n*12 + t*4);
    }
    float mx0=g.x, mx1=g.y, mx2=g.z, mx3=g.w;
    #pragma unroll
    for (int d=1; d<64; d<<=1){
      mx0=fmaxf(mx0,__shfl_xor(mx0,d,64)); mx1=fmaxf(mx1,__shfl_xor(mx1,d,64));
      mx2=fmaxf(mx2,__shfl_xor(mx2,d,64)); mx3=fmaxf(mx3,__shfl_xor(mx3,d,64));
    }
    float ex0=0,ex1=0,ex2=0,ex3=0;
    if (lane < deg){
      ex0=__expf(g.x-mx0); ex1=__expf(g.y-mx1); ex2=__expf(g.z-mx2); ex3=__expf(g.w-mx3);
    }
    float s0=ex0,s1=ex1,s2=ex2,s3=ex3;
    #pragma unroll
    for (int d=1; d<64; d<<=1){
      s0+=__shfl_xor(s0,d,64); s1+=__shfl_xor(s1,d,64);
      s2+=__shfl_xor(s2,d,64); s3+=__shfl_xor(s3,d,64);
    }
    float4 w; w.x=ex0/s0; w.y=ex1/s1; w.z=ex2/s2; w.w=ex3/s3;
    if (lane < deg) *(float4*)(attn + (size_t)m*4) = w;
    auto ldrow = [&](int j)->ushort4{
      int nn = __shfl(n, j, 64);
      return *(const ushort4*)(V16 + (size_t)nn*256 + (lane<<2));
    };
    ushort4 v0v,v1v,v2v,v3v;
    if (deg>0) v0v=ldrow(0);
    if (deg>1) v1v=ldrow(1);
    if (deg>2) v2v=ldrow(2);
    if (deg>3) v3v=ldrow(3);
    for (int j=0;j<deg;j+=4){
      { float wx=__shfl(w.x,j,64),wy=__shfl(w.y,j,64),wz=__shfl(w.z,j,64),wq=__shfl(w.w,j,64);
        a0+=wx*u2f(v0v.x); a1+=wy*u2f(v0v.y); a2+=wz*u2f(v0v.z); a3+=wq*u2f(v0v.w);
        if (j+4<deg) v0v=ldrow(j+4); }
      if (j+1<deg){
        float wx=__shfl(w.x,j+1,64),wy=__shfl(w.y,j+1,64),wz=__shfl(w.z,j+1,64),wq=__shfl(w.w,j+1,64);
        a0+=wx*u2f(v1v.x); a1+=wy*u2f(v1v.y); a2+=wz*u2f(v1v.z); a3+=wq*u2f(v1v.w);
        if (j+5<deg) v1v=ldrow(j+5); }
      if (j+2<deg){
        float wx=__shfl(w.x,j+2,64),wy=__shfl(w.y,j+2,64),wz=__shfl(w.z,j+2,64),wq=__shfl(w.w,j+2,64);
        a0+=wx*u2f(v2v.x); a1+=wy*u2f(v2v.y); a2+=wz*u2f(v2v.z); a3+=wq*u2f(v2v.w);
        if (j+6<deg) v2v=ldrow(j+6); }
      if (j+3<deg){
        float wx=__shfl(w.x,j+3,64),wy=__shfl(w.y,j+3,64),wz=__shfl(w.z,j+3,64),wq=__shfl(w.w,j+3,64);
        a0+=wx*u2f(v3v.x); a1+=wy*u2f(v3v.y); a2+=wz*u2f(v3v.z); a3+=wq*u2f(v3v.w);
        if (j+7<deg) v3v=ldrow(j+7); }
    }
  } else {
    float mx0=-1e30f, mx1=-1e30f, mx2=-1e30f, mx3=-1e30f;
    for (int i=beg+lane; i<end; i+=64){
      int m = ep[i]; int n = nidx[m];
      float4 g = *(const float4*)(G + (size_t)n*12 + t*4);
      mx0=fmaxf(mx0,g.x); mx1=fmaxf(mx1,g.y); mx2=fmaxf(mx2,g.z); mx3=fmaxf(mx3,g.w);
    }
    #pragma unroll
    for (int d=1; d<64; d<<=1){
      mx0=fmaxf(mx0,__shfl_xor(mx0,d,64)); mx1=fmaxf(mx1,__shfl_xor(mx1,d,64));
      mx2=fmaxf(mx2,__shfl_xor(mx2,d,64)); mx3=fmaxf(mx3,__shfl_xor(mx3,d,64));
    }
    float sm0=0,sm1=0,sm2=0,sm3=0;
    for (int i=beg+lane; i<end; i+=64){
      int m = ep[i]; int n = nidx[m];
      float4 g = *(const float4*)(G + (size_t)n*12 + t*4);
      sm0+=__expf(g.x-mx0); sm1+=__expf(g.y-mx1); sm2+=__expf(g.z-mx2); sm3+=__expf(g.w-mx3);
    }
    #pragma unroll
    for (int d=1; d<64; d<<=1){
      sm0+=__shfl_xor(sm0,d,64); sm1+=__shfl_xor(sm1,d,64);
      sm2+=__shfl_xor(sm2,d,64); sm3+=__shfl_xor(sm3,d,64);
    }
    float inv0=1.f/sm0, inv1=1.f/sm1, inv2=1.f/sm2, inv3=1.f/sm3;
    for (int i=beg+lane; i<end; i+=64){
      int m = ep[i]; int n = nidx[m];
      float4 g = *(const float4*)(G + (size_t)n*12 + t*4);
      float4 w;
      w.x=__expf(g.x-mx0)*inv0; w.y=__expf(g.y-mx1)*inv1;
      w.z=__expf(g.z-mx2)*inv2; w.w=__expf(g.w-mx3)*inv3;
      *(float4*)(attn + (size_t)m*4) = w;
    }
    for (int i=beg; i<end; ++i){
      int m = ep[i]; int n = nidx[m];
      float4 g = *(const float4*)(G + (size_t)n*12 + t*4);
      float w0=__expf(g.x-mx0)*inv0, w1=__expf(g.y-mx1)*inv1;
      float w2=__expf(g.z-mx2)*inv2, w3=__expf(g.w-mx3)*inv3;
      ushort4 v = *(const ushort4*)(V16 + (size_t)n*256 + lane*4);
      a0 += w0*u2f(v.x); a1 += w1*u2f(v.y); a2 += w2*u2f(v.z); a3 += w3*u2f(v.w);
    }
  }
  ushort4 ev; ev.x=f2u(a0); ev.y=f2u(a1); ev.z=f2u(a2); ev.w=f2u(a3);
  *(ushort4*)(EF16 + (size_t)e*256 + lane*4) = ev;
}

// ---------------- per-node gather + residual + LayerNorm (pipelined) ----------------
__global__ __launch_bounds__(256) void k_node(const int* __restrict__ noff, const int* __restrict__ np,
    const int* __restrict__ eidx, const float* __restrict__ attn, const unsigned short* __restrict__ EF16,
    const float* __restrict__ lng, const float* __restrict__ lnb,
    bf16* __restrict__ h16, void* __restrict__ outv, const int* __restrict__ flag, int last){
  int n = blockIdx.x*4 + (threadIdx.x>>6);
  int lane = threadIdx.x & 63;
  if (n >= N_) return;
  float f0=0,f1=0,f2=0,f3=0;
  int beg = noff[n], end = noff[n+1];
  int deg = end - beg;
  if (deg > 0 && deg <= 64){
    int i = beg + lane;
    int e = 0;
    float4 w; w.x=w.y=w.z=w.w=0.f;
    if (lane < deg){
      int m = np[i]; e = eidx[m];
      w = *(const float4*)(attn + (size_t)m*4);
    }
    auto ldrow = [&](int j)->ushort4{
      int ee = __shfl(e, j, 64);
      return *(const ushort4*)(EF16 + (size_t)ee*256 + (lane<<2));
    };
    ushort4 v0v,v1v,v2v,v3v;
    if (deg>0) v0v=ldrow(0);
    if (deg>1) v1v=ldrow(1);
    if (deg>2) v2v=ldrow(2);
    if (deg>3) v3v=ldrow(3);
    for (int j=0;j<deg;j+=4){
      { float wx=__shfl(w.x,j,64),wy=__shfl(w.y,j,64),wz=__shfl(w.z,j,64),wq=__shfl(w.w,j,64);
        f0+=wx*u2f(v0v.x); f1+=wy*u2f(v0v.y); f2+=wz*u2f(v0v.z); f3+=wq*u2f(v0v.w);
        if (j+4<deg) v0v=ldrow(j+4); }
      if (j+1<deg){
        float wx=__shfl(w.x,j+1,64),wy=__shfl(w.y,j+1,64),wz=__shfl(w.z,j+1,64),wq=__shfl(w.w,j+1,64);
        f0+=wx*u2f(v1v.x); f1+=wy*u2f(v1v.y); f2+=wz*u2f(v1v.z); f3+=wq*u2f(v1v.w);
        if (j+5<deg) v1v=ldrow(j+5); }
      if (j+2<deg){
        float wx=__shfl(w.x,j+2,64),wy=__shfl(w.y,j+2,64),wz=__shfl(w.z,j+2,64),wq=__shfl(w.w,j+2,64);
        f0+=wx*u2f(v2v.x); f1+=wy*u2f(v2v.y); f2+=wz*u2f(v2v.z); f3+=wq*u2f(v2v.w);
        if (j+6<deg) v2v=ldrow(j+6); }
      if (j+3<deg){
        float wx=__shfl(w.x,j+3,64),wy=__shfl(w.y,j+3,64),wz=__shfl(w.z,j+3,64),wq=__shfl(w.w,j+3,64);
        f0+=wx*u2f(v3v.x); f1+=wy*u2f(v3v.y); f2+=wz*u2f(v3v.z); f3+=wq*u2f(v3v.w);
        if (j+7<deg) v3v=ldrow(j+7); }
    }
  } else if (deg > 64){
    for (int i=beg; i<end; ++i){
      int m = np[i]; int e = eidx[m];
      float4 w = *(const float4*)(attn + (size_t)m*4);
      ushort4 v = *(const ushort4*)(EF16 + (size_t)e*256 + lane*4);
      f0 += w.x*u2f(v.x); f1 += w.y*u2f(v.y); f2 += w.z*u2f(v.z); f3 += w.w*u2f(v.w);
    }
  }
  const bf16* hp = h16 + (size_t)n*256;
  float h0 = b2f(hp[lane])+f0, h1 = b2f(hp[64+lane])+f1, h2 = b2f(hp[128+lane])+f2, h3 = b2f(hp[192+lane])+f3;
  float s = h0+h1+h2+h3;
  #pragma unroll
  for (int d=1; d<64; d<<=1) s += __shfl_xor(s,d,64);
  float mean = s * (1.f/256.f);
  float d0=h0-mean, d1=h1-mean, d2=h2-mean, d3=h3-mean;
  float vv = d0*d0+d1*d1+d2*d2+d3*d3;
  #pragma unroll
  for (int d=1; d<64; d<<=1) vv += __shfl_xor(vv,d,64);
  float rstd = rsqrtf(vv*(1.f/256.f) + 1e-5f);
  float o0 = d0*rstd*lng[lane]     + lnb[lane];
  float o1 = d1*rstd*lng[64+lane]  + lnb[64+lane];
  float o2 = d2*rstd*lng[128+lane] + lnb[128+lane];
  float o3 = d3*rstd*lng[192+lane] + lnb[192+lane];
  if (last){
    if (*flag){
      bf16* op = (bf16*)outv + (size_t)n*256;
      op[lane]=__float2bfloat16(o0); op[64+lane]=__float2bfloat16(o1);
      op[128+lane]=__float2bfloat16(o2); op[192+lane]=__float2bfloat16(o3);
    } else {
      float* op = (float*)outv + (size_t)n*256;
      op[lane]=o0; op[64+lane]=o1; op[128+lane]=o2; op[192+lane]=o3;
    }
  } else {
    bf16* o16 = h16 + (size_t)n*256;
    o16[lane]=__float2bfloat16(o0); o16[64+lane]=__float2bfloat16(o1);
    o16[128+lane]=__float2bfloat16(o2); o16[192+lane]=__float2bfloat16(o3);
  }
}

extern "C" void kernel_launch(void* const* d_in, const int* in_sizes, int n_in,
                              void* d_out, int out_size, void* d_ws, size_t ws_size,
                              hipStream_t stream){
  const void* x    = d_in[0];
  const int* ntype = (const int*)d_in[1];
  const int* etype = (const int*)d_in[2];
  const int* nidx  = (const int*)d_in[3];
  const int* eidx  = (const int*)d_in[4];
  (void)in_sizes; (void)n_in; (void)out_size; (void)ws_size;

  char* ws = (char*)d_ws;
  size_t o = 0;
  auto alloc = [&](size_t b)->char*{ char* r = ws + o; o = (o + b + 255) & ~(size_t)255; return r; };
  int*   flag = (int*)  alloc(256);
  char*  R2   =         alloc((size_t)20000000);          // Hb16+S (gemm->gate) / attn+EF16 (edge->node)
  float* G    = (float*)alloc((size_t)N_*12*4);
  float* tq_f  = (float*)alloc(1536*4);
  float* w1_f  = (float*)alloc(81920*4);
  float* b1_f  = (float*)alloc(256*4);
  float* w2_f  = (float*)alloc(256*4);
  float* b2_f  = (float*)alloc(8*4);
  float* wq_f  = (float*)alloc(131072*4);
  float* wv_f  = (float*)alloc(131072*4);
  float* ec_f  = (float*)alloc(1536*4);
  float* lng_f = (float*)alloc(512*4);
  float* lnb_f = (float*)alloc(512*4);
  float* pre   = (float*)alloc(768*4);
  int* cnt_e  = (int*)alloc((size_t)E_*4);
  int* cnt_n  = (int*)alloc((size_t)N_*4);
  int* eoff   = (int*)alloc((size_t)(E_+1)*4);
  int* noff   = (int*)alloc((size_t)(N_+1)*4);
  int* cur_e  = (int*)alloc((size_t)E_*4);
  int* cur_n  = (int*)alloc((size_t)N_*4);
  int* ep     = (int*)alloc((size_t)M_*4);
  int* np     = (int*)alloc((size_t)M_*4);
  int* bsum_e = (int*)alloc(256*4);
  int* bsum_n = (int*)alloc(256*4);
  bf16* h16   = (bf16*)alloc((size_t)NPAD_*256*2);        // 25.6 MB bf16 hidden state (A for MFMA)
  bf16* Bp    = (bf16*)alloc((size_t)2*448*256*2);
  bf16* V16   = (bf16*)alloc((size_t)N_*256*2);           // 25.6 MB interleaved [n][d][h]

  bf16*  Hb16 = (bf16*)R2;                                 // 12.8 MB
  float* S    = (float*)(R2 + 16777216);                   // 2.4 MB
  float* attn = (float*)R2;                                // 5.12 MB
  unsigned short* EF16 = (unsigned short*)(R2 + 5242880);  // 10.24 MB (ends 15.48M < S)

  // launch 1: sniff + zero counters
  k_sniffzero<<<275, 256, 0, stream>>>((const unsigned short*)x, flag, cnt_e, cnt_n);
  // launch 2: cvt16 + cvtall + hist
  k_prep<<<52614, 256, 0, stream>>>(
      x, h16,
      d_in[5], d_in[6], d_in[7], d_in[8], d_in[9],
      d_in[10], d_in[11], d_in[12], d_in[13], d_in[14],
      tq_f, w1_f, b1_f, w2_f, b2_f, wq_f, wv_f, ec_f, lng_f, lnb_f,
      eidx, nidx, cnt_e, cnt_n, flag);
  // launch 3: scan phase 1 + pre + bpack(with inline wqe)
  k_scan1w<<<NB_E+NB_N+3+896, 256, 0, stream>>>(
      cnt_e, eoff, bsum_e, cnt_n, noff, bsum_n,
      tq_f, w1_f, b1_f, pre, wv_f, wq_f, ec_f, Bp);
  // launch 4: scan phases 2+3
  k_scan23<<<NB_E+NB_N, 256, 0, stream>>>(bsum_e, eoff, cur_e, bsum_n, noff, cur_n);
  // launch 5: fill CSR
  k_fill<<<M_/256, 256, 0, stream>>>(eidx, nidx, cur_e, cur_n, ep, np);

  for (int l=0; l<2; ++l){
    k_mgemm<<<2737, 256, 0, stream>>>(h16, Bp + (size_t)l*448*256, V16, Hb16, S);
    k_gate<<<12500, 256, 0, stream>>>((const unsigned short*)Hb16, S, pre + l*384,
                                      w2_f + l*128, b2_f + l*4, ntype, G);
    k_edge<<<5000, 256, 0, stream>>>(eoff, ep, nidx, etype, G, (const unsigned short*)V16, attn, EF16);
    k_node<<<12500, 256, 0, stream>>>(noff, np, eidx, attn, EF16, lng_f + l*256, lnb_f + l*256,
                                      h16, d_out, flag, l==1);
  }
}

// Round 4
// 443.034 us; speedup vs baseline: 1.2345x; 1.0383x over previous
//
#include <hip/hip_runtime.h>
#include <hip/hip_bf16.h>

typedef __hip_bfloat16 bf16;
using short8  = __attribute__((ext_vector_type(8))) short;
using float4v = __attribute__((ext_vector_type(4))) float;

static constexpr int N_ = 50000;   // nodes
static constexpr int E_ = 20000;   // hyperedges
static constexpr int M_ = 320000;  // incidence pairs
static constexpr int NPAD_ = 50048;  // 391*128 rows for MFMA grid
static constexpr int NB_E = (E_+255)/256;   // 79
static constexpr int NB_N = (N_+255)/256;   // 196
static constexpr int CVTB_ = 6250;          // 12.8M elems / (256 thr * 8 elem)

__device__ __forceinline__ float b2f(bf16 v){ return __bfloat162float(v); }
__device__ __forceinline__ float sigm(float x){ return 1.f/(1.f+__expf(-x)); }
__device__ __forceinline__ float u2f(unsigned short u){ return __uint_as_float(((unsigned)u)<<16); }
__device__ __forceinline__ unsigned short f2u(float f){ bf16 t=__float2bfloat16(f); return *(unsigned short*)&t; }

// ---------------- sniff + zero counters (launch 1) ----------------
__global__ __launch_bounds__(256) void k_sniffzero(const unsigned short* __restrict__ xb, int* flag,
                                                   int* cnt_e, int* cnt_n){
  int b = blockIdx.x, tid = threadIdx.x;
  if (b == 0){
    int sane = 0;
    for (int i = tid; i < 4096; i += 256){
      unsigned short u = xb[2*i];
      int ex = (u >> 7) & 0xFF;
      if ((u & 0x7FFF) == 0 || (ex >= 117 && ex <= 137)) sane++;
    }
    #pragma unroll
    for (int d=1; d<64; d<<=1) sane += __shfl_xor(sane, d, 64);
    __shared__ int wsh[4];
    if ((tid&63)==0) wsh[tid>>6] = sane;
    __syncthreads();
    if (tid==0){
      int tot = wsh[0]+wsh[1]+wsh[2]+wsh[3];
      *flag = (tot > 2048) ? 1 : 0;    // 1 = bf16 storage
    }
  } else {
    int i = (b-1)*256 + tid;
    if (i < E_) cnt_e[i] = 0;
    else if (i < E_+N_) cnt_n[i-E_] = 0;
  }
}

// ---------------- prep: cvt16(vectorized) + cvtall + hist in one launch (launch 2) ----------------
// ranges: [0,6250) cvt16 x8-vectorized, [6250,7614) cvtall, [7614,8864) hist
__global__ __launch_bounds__(256) void k_prep(
    const void* __restrict__ x, bf16* __restrict__ h16,
    const void* s0, const void* s1, const void* s2, const void* s3, const void* s4,
    const void* s5, const void* s6, const void* s7, const void* s8, const void* s9,
    float* d0, float* d1, float* d2, float* d3, float* d4,
    float* d5, float* d6, float* d7, float* d8, float* d9,
    const int* __restrict__ eidx, const int* __restrict__ nidx,
    int* cnt_e, int* cnt_n,
    const int* __restrict__ flag){
  int b = blockIdx.x, t = threadIdx.x;
  if (b < CVTB_){
    size_t i0 = ((size_t)b*256 + t) * 8;          // 6250*256*8 == 12.8M == N_*256
    if (*flag){
      short8 v = *(const short8*)((const unsigned short*)x + i0);
      *(short8*)(h16 + i0) = v;
    } else {
      const float* xf = (const float*)x + i0;
      float4 a = *(const float4*)xf;
      float4 c = *(const float4*)(xf + 4);
      short8 v;
      v[0]=(short)f2u(a.x); v[1]=(short)f2u(a.y); v[2]=(short)f2u(a.z); v[3]=(short)f2u(a.w);
      v[4]=(short)f2u(c.x); v[5]=(short)f2u(c.y); v[6]=(short)f2u(c.z); v[7]=(short)f2u(c.w);
      *(short8*)(h16 + i0) = v;
    }
    return;
  }
  if (b < CVTB_+1364){
    int i = (b-CVTB_)*256 + t;
    const void* src; float* dst; int off;
    if      (i < 1536)            { src=s0; dst=d0; off=i; }
    else if (i < 1536+81920)      { src=s1; dst=d1; off=i-1536; }
    else if (i < 83712+256)       { src=s2; dst=d2; off=i-83712; }
    else if (i < 83968+256)       { src=s3; dst=d3; off=i-83968; }
    else if (i < 84224+8)         { src=s4; dst=d4; off=i-84224; }
    else if (i < 84232+131072)    { src=s5; dst=d5; off=i-84232; }
    else if (i < 215304+131072)   { src=s6; dst=d6; off=i-215304; }
    else if (i < 346376+1536)     { src=s7; dst=d7; off=i-346376; }
    else if (i < 347912+512)      { src=s8; dst=d8; off=i-347912; }
    else if (i < 348424+512)      { src=s9; dst=d9; off=i-348424; }
    else return;
    if (*flag) dst[off] = b2f(((const bf16*)src)[off]);
    else       dst[off] = ((const float*)src)[off];
    return;
  }
  int m = (b-(CVTB_+1364))*256 + t;
  if (m < M_){ atomicAdd(&cnt_e[eidx[m]],1); atomicAdd(&cnt_n[nidx[m]],1); }
}

// ---------------- scan phase 1 ----------------
__device__ __forceinline__ void scan1_body(const int* cnt, int* off, int* bsum, int n, int blk){
  int tid = threadIdx.x, lane = tid&63, wid = tid>>6;
  int i = blk*256 + tid;
  int v = (i<n)? cnt[i] : 0;
  int s = v;
  #pragma unroll
  for (int d=1; d<64; d<<=1){ int t = __shfl_up(s, d, 64); if (lane>=d) s += t; }
  __shared__ int ws[4]; __shared__ int wo[4];
  if (lane==63) ws[wid] = s;
  __syncthreads();
  if (tid==0){ int a=0; for (int k=0;k<4;k++){ int t=ws[k]; wo[k]=a; a+=t; } bsum[blk]=a; }
  __syncthreads();
  if (i<n) off[i] = wo[wid] + s - v;
}

// scan1 + pre + bpack(with inline wqe) in one launch (launch 3)
__global__ __launch_bounds__(256) void k_scan1w(
    const int* __restrict__ cnt_e, int* __restrict__ eoff, int* bsum_e,
    const int* __restrict__ cnt_n, int* __restrict__ noff, int* bsum_n,
    const float* __restrict__ tq_f, const float* __restrict__ w1_f, const float* __restrict__ b1_f,
    float* __restrict__ pre,
    const float* __restrict__ wv_f, const float* __restrict__ wq_f, const float* __restrict__ ec_f,
    bf16* __restrict__ Bp){
  int b = blockIdx.x;
  if (b < NB_E){ scan1_body(cnt_e, eoff, bsum_e, E_, b); return; }
  if (b < NB_E+NB_N){ scan1_body(cnt_n, noff, bsum_n, N_, b-NB_E); return; }
  int b2 = b - (NB_E+NB_N);
  if (b2 < 3){
    int idx = b2*256 + threadIdx.x;
    if (idx >= 768) return;
    int l = idx / 384, r = idx % 384;
    int t = r / 128, r2 = r % 128;
    int h = r2 >> 5, k = r2 & 31;
    const float* tp = tq_f + ((l*4+h)*3 + t)*64;
    const float* wp = w1_f + (size_t)((l*4+h)*32 + k)*320 + 256;
    float s = b1_f[(l*4+h)*32 + k];
    for (int d=0; d<64; ++d) s += tp[d]*wp[d];
    pre[(l*3+t)*128 + r2] = s;
    return;
  }
  int idx = (b2-3)*256 + threadIdx.x;
  if (idx >= 2*448*256) return;
  int l = idx / (448*256), r = idx % (448*256);
  int c = r >> 8, k = r & 255;
  float v = 0.f;
  if (c < 256){
    int dd = c >> 2, h = c & 3;
    v = wv_f[(size_t)l*65536 + (size_t)(h*64+dd)*256 + k];
  }
  else if (c < 384) v = w1_f[(size_t)l*40960 + (size_t)(c-256)*320 + k];
  else if (c < 396){
    int ht = c-384, h = ht/3, tt = ht%3;       // inline wqe dot (was k_wqe)
    const float* ecp = ec_f + ((l*4+h)*3 + tt)*64;
    const float* wqp = wq_f + (size_t)((l*4+h)*64)*256 + k;
    float s = 0.f;
    for (int o2=0; o2<64; ++o2) s += ecp[o2]*wqp[(size_t)o2*256];
    v = s;
  }
  Bp[idx] = __float2bfloat16(v);
}

// ---------------- scan phases 2+3 merged (launch 4) ----------------
__global__ __launch_bounds__(256) void k_scan23(const int* __restrict__ bsum_e, int* __restrict__ eoff, int* cur_e,
                                                const int* __restrict__ bsum_n, int* __restrict__ noff, int* cur_n){
  int b = blockIdx.x, t = threadIdx.x, lane = t&63, wid = t>>6;
  int nb, n, blk;
  const int* bsum; int* off; int* cur;
  if (b < NB_E){ nb=NB_E; n=E_; bsum=bsum_e; off=eoff; cur=cur_e; blk=b; }
  else         { nb=NB_N; n=N_; bsum=bsum_n; off=noff; cur=cur_n; blk=b-NB_E; }
  int v = (t < blk) ? bsum[t] : 0;   // blk <= 195 < 256
  #pragma unroll
  for (int d=1; d<64; d<<=1) v += __shfl_xor(v, d, 64);
  __shared__ int ws[4];
  if (lane==0) ws[wid] = v;
  __syncthreads();
  int p = ws[0]+ws[1]+ws[2]+ws[3];
  int i = blk*256 + t;
  if (i < n){ int e = off[i] + p; off[i] = e; cur[i] = e; }
  if (blk == nb-1 && t == 0) off[n] = p + bsum[nb-1];
}

__global__ __launch_bounds__(256) void k_fill(const int* __restrict__ eidx, const int* __restrict__ nidx,
                                              int* cur_e, int* cur_n, int* ep, int* np){
  int m = blockIdx.x*256 + threadIdx.x;
  if (m < M_){
    int p = atomicAdd(&cur_e[eidx[m]],1); ep[p]=m;
    int q = atomicAdd(&cur_n[nidx[m]],1); np[q]=m;
  }
}

// ---------------- MFMA GEMM: LDS-staged, XOR-swizzled, counted vmcnt ----------------
__global__ __launch_bounds__(256,3) void k_mgemm(const bf16* __restrict__ A16, const bf16* __restrict__ Bp,
    bf16* __restrict__ V16, bf16* __restrict__ Hb16, float* __restrict__ S){
  // bijective XCD swizzle (m204), nwg=2737=8*342+1; x fastest within an XCD -> A-panel L2 reuse
  int g = blockIdx.x;
  int xcd = g & 7, i7 = g >> 3;
  int wgid = (xcd==0) ? i7 : (343 + (xcd-1)*342 + i7);
  int x = wgid % 7, y = wgid / 7;

  int t = threadIdx.x;
  int wid = t >> 6, lane = t & 63;
  int q = lane >> 4, li = lane & 15;
  int row0blk = y*128;
  int col0 = x*64;
  int w32 = wid*32;

  __shared__ char lds[49152];   // [A0 16K][B0 8K][A1 16K][B1 8K]

  float4v acc[2][4];
  #pragma unroll
  for (int i=0;i<2;i++)
    #pragma unroll
    for (int j=0;j<4;j++) acc[i][j] = (float4v)(0.f);

  auto stage = [&](int st, int buf){
    const int k0 = st*64;
    char* lA = lds + (buf ? 24576 : 0);
    char* lB = lds + (buf ? 40960 : 16384);
    const bf16* Asrc = A16 + (size_t)row0blk*256 + k0;
    const bf16* Bsrc = Bp  + (size_t)col0*256 + k0;
    #pragma unroll
    for (int ra=0; ra<4; ++ra){
      int gidx = ra*256 + t;
      int r = gidx >> 3, c = gidx & 7;
      const bf16* src = Asrc + (size_t)r*256 + ((c ^ (r&7)) << 3);
      char* dst = lA + (ra*256 + wid*64)*16;   // wave-uniform base; HW adds lane*16
      __builtin_amdgcn_global_load_lds((const __attribute__((address_space(1))) void*)src,
                                       (__attribute__((address_space(3))) void*)dst, 16, 0, 0);
    }
    #pragma unroll
    for (int rb=0; rb<2; ++rb){
      int gidx = rb*256 + t;
      int r = gidx >> 3, c = gidx & 7;
      const bf16* src = Bsrc + (size_t)r*256 + ((c ^ (r&7)) << 3);
      char* dst = lB + (rb*256 + wid*64)*16;
      __builtin_amdgcn_global_load_lds((const __attribute__((address_space(1))) void*)src,
                                       (__attribute__((address_space(3))) void*)dst, 16, 0, 0);
    }
  };

  stage(0, 0);
  #pragma unroll
  for (int st=0; st<4; ++st){
    int bufc = st & 1;
    if (st < 3) stage(st+1, bufc^1);
    __builtin_amdgcn_sched_barrier(0);
    if (st < 3) asm volatile("s_waitcnt vmcnt(6)" ::: "memory");   // current tile done, next 6 in flight
    else        asm volatile("s_waitcnt vmcnt(0)" ::: "memory");
    __builtin_amdgcn_s_barrier();
    __builtin_amdgcn_sched_barrier(0);

    const char* cA = lds + (bufc ? 24576 : 0);
    const char* cB = lds + (bufc ? 40960 : 16384);
    short8 af[2][2], bfr[4][2];
    #pragma unroll
    for (int i=0;i<2;i++)
      #pragma unroll
      for (int k2=0;k2<2;k2++){
        int row = w32 + i*16 + li;
        int gr = (k2*4 + q) ^ (li & 7);
        af[i][k2] = *(const short8*)(cA + row*128 + gr*16);
      }
    #pragma unroll
    for (int j=0;j<4;j++)
      #pragma unroll
      for (int k2=0;k2<2;k2++){
        int row = j*16 + li;
        int gr = (k2*4 + q) ^ (li & 7);
        bfr[j][k2] = *(const short8*)(cB + row*128 + gr*16);
      }
    #pragma unroll
    for (int k2=0;k2<2;k2++)
      #pragma unroll
      for (int j=0;j<4;j++){
        acc[0][j] = __builtin_amdgcn_mfma_f32_16x16x32_bf16(af[0][k2], bfr[j][k2], acc[0][j],0,0,0);
        acc[1][j] = __builtin_amdgcn_mfma_f32_16x16x32_bf16(af[1][k2], bfr[j][k2], acc[1][j],0,0,0);
      }
    __builtin_amdgcn_sched_barrier(0);
    __builtin_amdgcn_s_barrier();
  }

  int row0 = row0blk + w32;
  #pragma unroll
  for (int i=0;i<2;i++){
    #pragma unroll
    for (int r=0;r<4;r++){
      int grow = row0 + i*16 + q*4 + r;
      if (grow >= N_) continue;
      #pragma unroll
      for (int j=0;j<4;j++){
        int gc = col0 + j*16 + li;
        float v = acc[i][j][r];
        if (gc < 256)      V16 [(size_t)grow*256 + gc]       = __float2bfloat16(v);  // contiguous (permuted)
        else if (gc < 384) Hb16[(size_t)grow*128 + gc - 256] = __float2bfloat16(v);
        else if (gc < 396) S   [(size_t)grow*12  + gc - 384] = v;
      }
    }
  }
}

// ---------------- per-node gate (Hb bf16) ----------------
__global__ __launch_bounds__(256) void k_gate(const unsigned short* __restrict__ Hb16, const float* __restrict__ S,
    const float* __restrict__ pre_l, const float* __restrict__ w2_l, const float* __restrict__ b2_l,
    const int* __restrict__ ntype, float* __restrict__ G){
  int node = blockIdx.x*4 + (threadIdx.x>>6);
  int lane = threadIdx.x & 63;
  if (node >= N_) return;
  int typ = ntype[node];
  const float* pr = pre_l + typ*128;
  float v0 = tanhf(u2f(Hb16[(size_t)node*128 + lane])      + pr[lane]);
  float v1 = tanhf(u2f(Hb16[(size_t)node*128 + 64 + lane]) + pr[64+lane]);
  float p0 = v0 * w2_l[lane];
  float p1 = v1 * w2_l[64+lane];
  #pragma unroll
  for (int d=1; d<32; d<<=1){ p0 += __shfl_xor(p0,d,64); p1 += __shfl_xor(p1,d,64); }
  float at0 = sigm(__shfl(p0, 0,64) + b2_l[0]);
  float at1 = sigm(__shfl(p0,32,64) + b2_l[1]);
  float at2 = sigm(__shfl(p1, 0,64) + b2_l[2]);
  float at3 = sigm(__shfl(p1,32,64) + b2_l[3]);
  if (lane < 12){
    int h = lane / 3, t = lane % 3;
    float sv = S[(size_t)node*12 + lane];
    float lr = (sv > 0.f) ? sv : 0.2f*sv;
    float av = (h==0)? at0 : (h==1)? at1 : (h==2)? at2 : at3;
    G[(size_t)node*12 + t*4 + h] = lr * av;
  }
}

// ---------------- per-edge softmax + edge_feat (single-pass, pipelined gather) ----------------
__global__ __launch_bounds__(256) void k_edge(const int* __restrict__ eoff, const int* __restrict__ ep,
    const int* __restrict__ nidx, const int* __restrict__ etype,
    const float* __restrict__ G, const unsigned short* __restrict__ V16,
    float* __restrict__ attn, unsigned short* __restrict__ EF16){
  int e = blockIdx.x*4 + (threadIdx.x>>6);
  int lane = threadIdx.x & 63;
  if (e >= E_) return;
  int beg = eoff[e], end = eoff[e+1];
  int deg = end - beg;
  if (deg == 0) return;
  int t = etype[e];
  float a0=0,a1=0,a2=0,a3=0;

  if (deg <= 64){
    int i = beg + lane;
    int m = -1, n = 0;
    float4 g; g.x=g.y=g.z=g.w=-1e30f;
    if (lane < deg){
      m = ep[i]; n = nidx[m];
      g = *(const float4*)(G + (size_t)n*12 + t*4);
    }
    float mx0=g.x, mx1=g.y, mx2=g.z, mx3=g.w;
    #pragma unroll
    for (int d=1; d<64; d<<=1){
      mx0=fmaxf(mx0,__shfl_xor(mx0,d,64)); mx1=fmaxf(mx1,__shfl_xor(mx1,d,64));
      mx2=fmaxf(mx2,__shfl_xor(mx2,d,64)); mx3=fmaxf(mx3,__shfl_xor(mx3,d,64));
    }
    float ex0=0,ex1=0,ex2=0,ex3=0;
    if (lane < deg){
      ex0=__expf(g.x-mx0); ex1=__expf(g.y-mx1); ex2=__expf(g.z-mx2); ex3=__expf(g.w-mx3);
    }
    float s0=ex0,s1=ex1,s2=ex2,s3=ex3;
    #pragma unroll
    for (int d=1; d<64; d<<=1){
      s0+=__shfl_xor(s0,d,64); s1+=__shfl_xor(s1,d,64);
      s2+=__shfl_xor(s2,d,64); s3+=__shfl_xor(s3,d,64);
    }
    float4 w; w.x=ex0/s0; w.y=ex1/s1; w.z=ex2/s2; w.w=ex3/s3;
    if (lane < deg) *(float4*)(attn + (size_t)m*4) = w;
    auto ldrow = [&](int j)->ushort4{
      int nn = __shfl(n, j, 64);
      return *(const ushort4*)(V16 + (size_t)nn*256 + (lane<<2));
    };
    ushort4 v0v,v1v,v2v,v3v;
    if (deg>0) v0v=ldrow(0);
    if (deg>1) v1v=ldrow(1);
    if (deg>2) v2v=ldrow(2);
    if (deg>3) v3v=ldrow(3);
    for (int j=0;j<deg;j+=4){
      { float wx=__shfl(w.x,j,64),wy=__shfl(w.y,j,64),wz=__shfl(w.z,j,64),wq=__shfl(w.w,j,64);
        a0+=wx*u2f(v0v.x); a1+=wy*u2f(v0v.y); a2+=wz*u2f(v0v.z); a3+=wq*u2f(v0v.w);
        if (j+4<deg) v0v=ldrow(j+4); }
      if (j+1<deg){
        float wx=__shfl(w.x,j+1,64),wy=__shfl(w.y,j+1,64),wz=__shfl(w.z,j+1,64),wq=__shfl(w.w,j+1,64);
        a0+=wx*u2f(v1v.x); a1+=wy*u2f(v1v.y); a2+=wz*u2f(v1v.z); a3+=wq*u2f(v1v.w);
        if (j+5<deg) v1v=ldrow(j+5); }
      if (j+2<deg){
        float wx=__shfl(w.x,j+2,64),wy=__shfl(w.y,j+2,64),wz=__shfl(w.z,j+2,64),wq=__shfl(w.w,j+2,64);
        a0+=wx*u2f(v2v.x); a1+=wy*u2f(v2v.y); a2+=wz*u2f(v2v.z); a3+=wq*u2f(v2v.w);
        if (j+6<deg) v2v=ldrow(j+6); }
      if (j+3<deg){
        float wx=__shfl(w.x,j+3,64),wy=__shfl(w.y,j+3,64),wz=__shfl(w.z,j+3,64),wq=__shfl(w.w,j+3,64);
        a0+=wx*u2f(v3v.x); a1+=wy*u2f(v3v.y); a2+=wz*u2f(v3v.z); a3+=wq*u2f(v3v.w);
        if (j+7<deg) v3v=ldrow(j+7); }
    }
  } else {
    float mx0=-1e30f, mx1=-1e30f, mx2=-1e30f, mx3=-1e30f;
    for (int i=beg+lane; i<end; i+=64){
      int m = ep[i]; int n = nidx[m];
      float4 g = *(const float4*)(G + (size_t)n*12 + t*4);
      mx0=fmaxf(mx0,g.x); mx1=fmaxf(mx1,g.y); mx2=fmaxf(mx2,g.z); mx3=fmaxf(mx3,g.w);
    }
    #pragma unroll
    for (int d=1; d<64; d<<=1){
      mx0=fmaxf(mx0,__shfl_xor(mx0,d,64)); mx1=fmaxf(mx1,__shfl_xor(mx1,d,64));
      mx2=fmaxf(mx2,__shfl_xor(mx2,d,64)); mx3=fmaxf(mx3,__shfl_xor(mx3,d,64));
    }
    float sm0=0,sm1=0,sm2=0,sm3=0;
    for (int i=beg+lane; i<end; i+=64){
      int m = ep[i]; int n = nidx[m];
      float4 g = *(const float4*)(G + (size_t)n*12 + t*4);
      sm0+=__expf(g.x-mx0); sm1+=__expf(g.y-mx1); sm2+=__expf(g.z-mx2); sm3+=__expf(g.w-mx3);
    }
    #pragma unroll
    for (int d=1; d<64; d<<=1){
      sm0+=__shfl_xor(sm0,d,64); sm1+=__shfl_xor(sm1,d,64);
      sm2+=__shfl_xor(sm2,d,64); sm3+=__shfl_xor(sm3,d,64);
    }
    float inv0=1.f/sm0, inv1=1.f/sm1, inv2=1.f/sm2, inv3=1.f/sm3;
    for (int i=beg+lane; i<end; i+=64){
      int m = ep[i]; int n = nidx[m];
      float4 g = *(const float4*)(G + (size_t)n*12 + t*4);
      float4 w;
      w.x=__expf(g.x-mx0)*inv0; w.y=__expf(g.y-mx1)*inv1;
      w.z=__expf(g.z-mx2)*inv2; w.w=__expf(g.w-mx3)*inv3;
      *(float4*)(attn + (size_t)m*4) = w;
    }
    for (int i=beg; i<end; ++i){
      int m = ep[i]; int n = nidx[m];
      float4 g = *(const float4*)(G + (size_t)n*12 + t*4);
      float w0=__expf(g.x-mx0)*inv0, w1=__expf(g.y-mx1)*inv1;
      float w2=__expf(g.z-mx2)*inv2, w3=__expf(g.w-mx3)*inv3;
      ushort4 v = *(const ushort4*)(V16 + (size_t)n*256 + lane*4);
      a0 += w0*u2f(v.x); a1 += w1*u2f(v.y); a2 += w2*u2f(v.z); a3 += w3*u2f(v.w);
    }
  }
  ushort4 ev; ev.x=f2u(a0); ev.y=f2u(a1); ev.z=f2u(a2); ev.w=f2u(a3);
  *(ushort4*)(EF16 + (size_t)e*256 + lane*4) = ev;
}

// ---------------- per-node gather + residual + LayerNorm (pipelined) ----------------
__global__ __launch_bounds__(256) void k_node(const int* __restrict__ noff, const int* __restrict__ np,
    const int* __restrict__ eidx, const float* __restrict__ attn, const unsigned short* __restrict__ EF16,
    const float* __restrict__ lng, const float* __restrict__ lnb,
    bf16* __restrict__ h16, void* __restrict__ outv, const int* __restrict__ flag, int last){
  int n = blockIdx.x*4 + (threadIdx.x>>6);
  int lane = threadIdx.x & 63;
  if (n >= N_) return;
  float f0=0,f1=0,f2=0,f3=0;
  int beg = noff[n], end = noff[n+1];
  int deg = end - beg;
  if (deg > 0 && deg <= 64){
    int i = beg + lane;
    int e = 0;
    float4 w; w.x=w.y=w.z=w.w=0.f;
    if (lane < deg){
      int m = np[i]; e = eidx[m];
      w = *(const float4*)(attn + (size_t)m*4);
    }
    auto ldrow = [&](int j)->ushort4{
      int ee = __shfl(e, j, 64);
      return *(const ushort4*)(EF16 + (size_t)ee*256 + (lane<<2));
    };
    ushort4 v0v,v1v,v2v,v3v;
    if (deg>0) v0v=ldrow(0);
    if (deg>1) v1v=ldrow(1);
    if (deg>2) v2v=ldrow(2);
    if (deg>3) v3v=ldrow(3);
    for (int j=0;j<deg;j+=4){
      { float wx=__shfl(w.x,j,64),wy=__shfl(w.y,j,64),wz=__shfl(w.z,j,64),wq=__shfl(w.w,j,64);
        f0+=wx*u2f(v0v.x); f1+=wy*u2f(v0v.y); f2+=wz*u2f(v0v.z); f3+=wq*u2f(v0v.w);
        if (j+4<deg) v0v=ldrow(j+4); }
      if (j+1<deg){
        float wx=__shfl(w.x,j+1,64),wy=__shfl(w.y,j+1,64),wz=__shfl(w.z,j+1,64),wq=__shfl(w.w,j+1,64);
        f0+=wx*u2f(v1v.x); f1+=wy*u2f(v1v.y); f2+=wz*u2f(v1v.z); f3+=wq*u2f(v1v.w);
        if (j+5<deg) v1v=ldrow(j+5); }
      if (j+2<deg){
        float wx=__shfl(w.x,j+2,64),wy=__shfl(w.y,j+2,64),wz=__shfl(w.z,j+2,64),wq=__shfl(w.w,j+2,64);
        f0+=wx*u2f(v2v.x); f1+=wy*u2f(v2v.y); f2+=wz*u2f(v2v.z); f3+=wq*u2f(v2v.w);
        if (j+6<deg) v2v=ldrow(j+6); }
      if (j+3<deg){
        float wx=__shfl(w.x,j+3,64),wy=__shfl(w.y,j+3,64),wz=__shfl(w.z,j+3,64),wq=__shfl(w.w,j+3,64);
        f0+=wx*u2f(v3v.x); f1+=wy*u2f(v3v.y); f2+=wz*u2f(v3v.z); f3+=wq*u2f(v3v.w);
        if (j+7<deg) v3v=ldrow(j+7); }
    }
  } else if (deg > 64){
    for (int i=beg; i<end; ++i){
      int m = np[i]; int e = eidx[m];
      float4 w = *(const float4*)(attn + (size_t)m*4);
      ushort4 v = *(const ushort4*)(EF16 + (size_t)e*256 + lane*4);
      f0 += w.x*u2f(v.x); f1 += w.y*u2f(v.y); f2 += w.z*u2f(v.z); f3 += w.w*u2f(v.w);
    }
  }
  const bf16* hp = h16 + (size_t)n*256;
  float h0 = b2f(hp[lane])+f0, h1 = b2f(hp[64+lane])+f1, h2 = b2f(hp[128+lane])+f2, h3 = b2f(hp[192+lane])+f3;
  float s = h0+h1+h2+h3;
  #pragma unroll
  for (int d=1; d<64; d<<=1) s += __shfl_xor(s,d,64);
  float mean = s * (1.f/256.f);
  float d0=h0-mean, d1=h1-mean, d2=h2-mean, d3=h3-mean;
  float vv = d0*d0+d1*d1+d2*d2+d3*d3;
  #pragma unroll
  for (int d=1; d<64; d<<=1) vv += __shfl_xor(vv,d,64);
  float rstd = rsqrtf(vv*(1.f/256.f) + 1e-5f);
  float o0 = d0*rstd*lng[lane]     + lnb[lane];
  float o1 = d1*rstd*lng[64+lane]  + lnb[64+lane];
  float o2 = d2*rstd*lng[128+lane] + lnb[128+lane];
  float o3 = d3*rstd*lng[192+lane] + lnb[192+lane];
  if (last){
    if (*flag){
      bf16* op = (bf16*)outv + (size_t)n*256;
      op[lane]=__float2bfloat16(o0); op[64+lane]=__float2bfloat16(o1);
      op[128+lane]=__float2bfloat16(o2); op[192+lane]=__float2bfloat16(o3);
    } else {
      float* op = (float*)outv + (size_t)n*256;
      op[lane]=o0; op[64+lane]=o1; op[128+lane]=o2; op[192+lane]=o3;
    }
  } else {
    bf16* o16 = h16 + (size_t)n*256;
    o16[lane]=__float2bfloat16(o0); o16[64+lane]=__float2bfloat16(o1);
    o16[128+lane]=__float2bfloat16(o2); o16[192+lane]=__float2bfloat16(o3);
  }
}

extern "C" void kernel_launch(void* const* d_in, const int* in_sizes, int n_in,
                              void* d_out, int out_size, void* d_ws, size_t ws_size,
                              hipStream_t stream){
  const void* x    = d_in[0];
  const int* ntype = (const int*)d_in[1];
  const int* etype = (const int*)d_in[2];
  const int* nidx  = (const int*)d_in[3];
  const int* eidx  = (const int*)d_in[4];
  (void)in_sizes; (void)n_in; (void)out_size; (void)ws_size;

  char* ws = (char*)d_ws;
  size_t o = 0;
  auto alloc = [&](size_t b)->char*{ char* r = ws + o; o = (o + b + 255) & ~(size_t)255; return r; };
  int*   flag = (int*)  alloc(256);
  char*  R2   =         alloc((size_t)20000000);          // Hb16+S (gemm->gate) / attn+EF16 (edge->node)
  float* G    = (float*)alloc((size_t)N_*12*4);
  float* tq_f  = (float*)alloc(1536*4);
  float* w1_f  = (float*)alloc(81920*4);
  float* b1_f  = (float*)alloc(256*4);
  float* w2_f  = (float*)alloc(256*4);
  float* b2_f  = (float*)alloc(8*4);
  float* wq_f  = (float*)alloc(131072*4);
  float* wv_f  = (float*)alloc(131072*4);
  float* ec_f  = (float*)alloc(1536*4);
  float* lng_f = (float*)alloc(512*4);
  float* lnb_f = (float*)alloc(512*4);
  float* pre   = (float*)alloc(768*4);
  int* cnt_e  = (int*)alloc((size_t)E_*4);
  int* cnt_n  = (int*)alloc((size_t)N_*4);
  int* eoff   = (int*)alloc((size_t)(E_+1)*4);
  int* noff   = (int*)alloc((size_t)(N_+1)*4);
  int* cur_e  = (int*)alloc((size_t)E_*4);
  int* cur_n  = (int*)alloc((size_t)N_*4);
  int* ep     = (int*)alloc((size_t)M_*4);
  int* np     = (int*)alloc((size_t)M_*4);
  int* bsum_e = (int*)alloc(256*4);
  int* bsum_n = (int*)alloc(256*4);
  bf16* h16   = (bf16*)alloc((size_t)NPAD_*256*2);        // 25.6 MB bf16 hidden state (A for MFMA)
  bf16* Bp    = (bf16*)alloc((size_t)2*448*256*2);
  bf16* V16   = (bf16*)alloc((size_t)N_*256*2);           // 25.6 MB interleaved [n][d][h]

  bf16*  Hb16 = (bf16*)R2;                                 // 12.8 MB
  float* S    = (float*)(R2 + 16777216);                   // 2.4 MB
  float* attn = (float*)R2;                                // 5.12 MB
  unsigned short* EF16 = (unsigned short*)(R2 + 5242880);  // 10.24 MB (ends 15.48M < S)

  // launch 1: sniff + zero counters
  k_sniffzero<<<275, 256, 0, stream>>>((const unsigned short*)x, flag, cnt_e, cnt_n);
  // launch 2: cvt16(vectorized) + cvtall + hist
  k_prep<<<CVTB_+1364+1250, 256, 0, stream>>>(
      x, h16,
      d_in[5], d_in[6], d_in[7], d_in[8], d_in[9],
      d_in[10], d_in[11], d_in[12], d_in[13], d_in[14],
      tq_f, w1_f, b1_f, w2_f, b2_f, wq_f, wv_f, ec_f, lng_f, lnb_f,
      eidx, nidx, cnt_e, cnt_n, flag);
  // launch 3: scan phase 1 + pre + bpack(with inline wqe)
  k_scan1w<<<NB_E+NB_N+3+896, 256, 0, stream>>>(
      cnt_e, eoff, bsum_e, cnt_n, noff, bsum_n,
      tq_f, w1_f, b1_f, pre, wv_f, wq_f, ec_f, Bp);
  // launch 4: scan phases 2+3
  k_scan23<<<NB_E+NB_N, 256, 0, stream>>>(bsum_e, eoff, cur_e, bsum_n, noff, cur_n);
  // launch 5: fill CSR
  k_fill<<<M_/256, 256, 0, stream>>>(eidx, nidx, cur_e, cur_n, ep, np);

  for (int l=0; l<2; ++l){
    k_mgemm<<<2737, 256, 0, stream>>>(h16, Bp + (size_t)l*448*256, V16, Hb16, S);
    k_gate<<<12500, 256, 0, stream>>>((const unsigned short*)Hb16, S, pre + l*384,
                                      w2_f + l*128, b2_f + l*4, ntype, G);
    k_edge<<<5000, 256, 0, stream>>>(eoff, ep, nidx, etype, G, (const unsigned short*)V16, attn, EF16);
    k_node<<<12500, 256, 0, stream>>>(noff, np, eidx, attn, EF16, lng_f + l*256, lnb_f + l*256,
                                      h16, d_out, flag, l==1);
  }
}

// Round 5
// 440.672 us; speedup vs baseline: 1.2411x; 1.0054x over previous
//
#include <hip/hip_runtime.h>
#include <hip/hip_bf16.h>

typedef __hip_bfloat16 bf16;
using short8  = __attribute__((ext_vector_type(8))) short;
using float4v = __attribute__((ext_vector_type(4))) float;

static constexpr int N_ = 50000;   // nodes
static constexpr int E_ = 20000;   // hyperedges
static constexpr int M_ = 320000;  // incidence pairs
static constexpr int NPAD_ = 50048;  // 391*128 rows for MFMA grid
static constexpr int NB_E = (E_+255)/256;   // 79
static constexpr int NB_N = (N_+255)/256;   // 196
static constexpr int CVTB_ = 6250;          // 12.8M elems / (256 thr * 8 elem)
static constexpr int HISTB_ = 1250;         // 320K / 256
static constexpr int CVTALLB_ = 1364;
static constexpr int NREP_ = 8;             // histogram replication factor

__device__ __forceinline__ float b2f(bf16 v){ return __bfloat162float(v); }
__device__ __forceinline__ float sigm(float x){ return 1.f/(1.f+__expf(-x)); }
__device__ __forceinline__ float u2f(unsigned short u){ return __uint_as_float(((unsigned)u)<<16); }
__device__ __forceinline__ unsigned short f2u(float f){ bf16 t=__float2bfloat16(f); return *(unsigned short*)&t; }

// ---------------- sniff + zero replicated counters (launch 1) ----------------
__global__ __launch_bounds__(256) void k_sniffzero(const unsigned short* __restrict__ xb, int* flag,
                                                   int* cnt_e, int* cnt_n){
  int b = blockIdx.x, tid = threadIdx.x;
  if (b == 0){
    int sane = 0;
    for (int i = tid; i < 4096; i += 256){
      unsigned short u = xb[2*i];
      int ex = (u >> 7) & 0xFF;
      if ((u & 0x7FFF) == 0 || (ex >= 117 && ex <= 137)) sane++;
    }
    #pragma unroll
    for (int d=1; d<64; d<<=1) sane += __shfl_xor(sane, d, 64);
    __shared__ int wsh[4];
    if ((tid&63)==0) wsh[tid>>6] = sane;
    __syncthreads();
    if (tid==0){
      int tot = wsh[0]+wsh[1]+wsh[2]+wsh[3];
      *flag = (tot > 2048) ? 1 : 0;    // 1 = bf16 storage
    }
  } else {
    int i = (b-1)*256 + tid;
    if (i < NREP_*E_) cnt_e[i] = 0;
    else if (i < NREP_*E_ + NREP_*N_) cnt_n[i - NREP_*E_] = 0;
  }
}

// ---------------- prep: hist(replicated, FIRST) + cvtall + cvt16 in one launch (launch 2) ----------------
// ranges: [0,1250) hist, [1250,2614) cvtall, [2614,8864) cvt16 x8-vectorized
__global__ __launch_bounds__(256) void k_prep(
    const void* __restrict__ x, bf16* __restrict__ h16,
    const void* s0, const void* s1, const void* s2, const void* s3, const void* s4,
    const void* s5, const void* s6, const void* s7, const void* s8, const void* s9,
    float* d0, float* d1, float* d2, float* d3, float* d4,
    float* d5, float* d6, float* d7, float* d8, float* d9,
    const int* __restrict__ eidx, const int* __restrict__ nidx,
    int* cnt_e, int* cnt_n,
    const int* __restrict__ flag){
  int b = blockIdx.x, t = threadIdx.x;
  if (b < HISTB_){
    int m = b*256 + t;
    int rep = b & (NREP_-1);
    if (m < M_){
      atomicAdd(&cnt_e[rep*E_ + eidx[m]],1);
      atomicAdd(&cnt_n[rep*N_ + nidx[m]],1);
    }
    return;
  }
  if (b < HISTB_+CVTALLB_){
    int i = (b-HISTB_)*256 + t;
    const void* src; float* dst; int off;
    if      (i < 1536)            { src=s0; dst=d0; off=i; }
    else if (i < 1536+81920)      { src=s1; dst=d1; off=i-1536; }
    else if (i < 83712+256)       { src=s2; dst=d2; off=i-83712; }
    else if (i < 83968+256)       { src=s3; dst=d3; off=i-83968; }
    else if (i < 84224+8)         { src=s4; dst=d4; off=i-84224; }
    else if (i < 84232+131072)    { src=s5; dst=d5; off=i-84232; }
    else if (i < 215304+131072)   { src=s6; dst=d6; off=i-215304; }
    else if (i < 346376+1536)     { src=s7; dst=d7; off=i-346376; }
    else if (i < 347912+512)      { src=s8; dst=d8; off=i-347912; }
    else if (i < 348424+512)      { src=s9; dst=d9; off=i-348424; }
    else return;
    if (*flag) dst[off] = b2f(((const bf16*)src)[off]);
    else       dst[off] = ((const float*)src)[off];
    return;
  }
  size_t i0 = ((size_t)(b-(HISTB_+CVTALLB_))*256 + t) * 8;   // 6250*256*8 == N_*256
  if (*flag){
    short8 v = *(const short8*)((const unsigned short*)x + i0);
    *(short8*)(h16 + i0) = v;
  } else {
    const float* xf = (const float*)x + i0;
    float4 a = *(const float4*)xf;
    float4 c = *(const float4*)(xf + 4);
    short8 v;
    v[0]=(short)f2u(a.x); v[1]=(short)f2u(a.y); v[2]=(short)f2u(a.z); v[3]=(short)f2u(a.w);
    v[4]=(short)f2u(c.x); v[5]=(short)f2u(c.y); v[6]=(short)f2u(c.z); v[7]=(short)f2u(c.w);
    *(short8*)(h16 + i0) = v;
  }
}

// ---------------- scan phase 1 (sums NREP_ replicated histograms) ----------------
__device__ __forceinline__ void scan1_body(const int* cnt, int* off, int* bsum, int n, int blk){
  int tid = threadIdx.x, lane = tid&63, wid = tid>>6;
  int i = blk*256 + tid;
  int v = 0;
  if (i < n){
    #pragma unroll
    for (int c=0;c<NREP_;++c) v += cnt[c*n + i];
  }
  int s = v;
  #pragma unroll
  for (int d=1; d<64; d<<=1){ int t = __shfl_up(s, d, 64); if (lane>=d) s += t; }
  __shared__ int ws[4]; __shared__ int wo[4];
  if (lane==63) ws[wid] = s;
  __syncthreads();
  if (tid==0){ int a=0; for (int k=0;k<4;k++){ int t=ws[k]; wo[k]=a; a+=t; } bsum[blk]=a; }
  __syncthreads();
  if (i<n) off[i] = wo[wid] + s - v;
}

// scan1 + pre + bpack(with inline wqe) in one launch (launch 3)
__global__ __launch_bounds__(256) void k_scan1w(
    const int* __restrict__ cnt_e, int* __restrict__ eoff, int* bsum_e,
    const int* __restrict__ cnt_n, int* __restrict__ noff, int* bsum_n,
    const float* __restrict__ tq_f, const float* __restrict__ w1_f, const float* __restrict__ b1_f,
    float* __restrict__ pre,
    const float* __restrict__ wv_f, const float* __restrict__ wq_f, const float* __restrict__ ec_f,
    bf16* __restrict__ Bp){
  int b = blockIdx.x;
  if (b < NB_E){ scan1_body(cnt_e, eoff, bsum_e, E_, b); return; }
  if (b < NB_E+NB_N){ scan1_body(cnt_n, noff, bsum_n, N_, b-NB_E); return; }
  int b2 = b - (NB_E+NB_N);
  if (b2 < 3){
    int idx = b2*256 + threadIdx.x;
    if (idx >= 768) return;
    int l = idx / 384, r = idx % 384;
    int t = r / 128, r2 = r % 128;
    int h = r2 >> 5, k = r2 & 31;
    const float* tp = tq_f + ((l*4+h)*3 + t)*64;
    const float* wp = w1_f + (size_t)((l*4+h)*32 + k)*320 + 256;
    float s = b1_f[(l*4+h)*32 + k];
    for (int d=0; d<64; ++d) s += tp[d]*wp[d];
    pre[(l*3+t)*128 + r2] = s;
    return;
  }
  int idx = (b2-3)*256 + threadIdx.x;
  if (idx >= 2*448*256) return;
  int l = idx / (448*256), r = idx % (448*256);
  int c = r >> 8, k = r & 255;
  float v = 0.f;
  if (c < 256){
    int dd = c >> 2, h = c & 3;
    v = wv_f[(size_t)l*65536 + (size_t)(h*64+dd)*256 + k];
  }
  else if (c < 384) v = w1_f[(size_t)l*40960 + (size_t)(c-256)*320 + k];
  else if (c < 396){
    int ht = c-384, h = ht/3, tt = ht%3;       // inline wqe dot (was k_wqe)
    const float* ecp = ec_f + ((l*4+h)*3 + tt)*64;
    const float* wqp = wq_f + (size_t)((l*4+h)*64)*256 + k;
    float s = 0.f;
    for (int o2=0; o2<64; ++o2) s += ecp[o2]*wqp[(size_t)o2*256];
    v = s;
  }
  Bp[idx] = __float2bfloat16(v);
}

// ---------------- scan phases 2+3 merged (launch 4) ----------------
__global__ __launch_bounds__(256) void k_scan23(const int* __restrict__ bsum_e, int* __restrict__ eoff, int* cur_e,
                                                const int* __restrict__ bsum_n, int* __restrict__ noff, int* cur_n){
  int b = blockIdx.x, t = threadIdx.x, lane = t&63, wid = t>>6;
  int nb, n, blk;
  const int* bsum; int* off; int* cur;
  if (b < NB_E){ nb=NB_E; n=E_; bsum=bsum_e; off=eoff; cur=cur_e; blk=b; }
  else         { nb=NB_N; n=N_; bsum=bsum_n; off=noff; cur=cur_n; blk=b-NB_E; }
  int v = (t < blk) ? bsum[t] : 0;   // blk <= 195 < 256
  #pragma unroll
  for (int d=1; d<64; d<<=1) v += __shfl_xor(v, d, 64);
  __shared__ int ws[4];
  if (lane==0) ws[wid] = v;
  __syncthreads();
  int p = ws[0]+ws[1]+ws[2]+ws[3];
  int i = blk*256 + t;
  if (i < n){ int e = off[i] + p; off[i] = e; cur[i] = e; }
  if (blk == nb-1 && t == 0) off[n] = p + bsum[nb-1];
}

__global__ __launch_bounds__(256) void k_fill(const int* __restrict__ eidx, const int* __restrict__ nidx,
                                              int* cur_e, int* cur_n, int* ep, int* np){
  int m = blockIdx.x*256 + threadIdx.x;
  if (m < M_){
    int p = atomicAdd(&cur_e[eidx[m]],1); ep[p]=m;
    int q = atomicAdd(&cur_n[nidx[m]],1); np[q]=m;
  }
}

// ---------------- MFMA GEMM: LDS-staged, XOR-swizzled, counted vmcnt ----------------
__global__ __launch_bounds__(256,3) void k_mgemm(const bf16* __restrict__ A16, const bf16* __restrict__ Bp,
    bf16* __restrict__ V16, bf16* __restrict__ Hb16, float* __restrict__ S){
  // bijective XCD swizzle (m204), nwg=2737=8*342+1; x fastest within an XCD -> A-panel L2 reuse
  int g = blockIdx.x;
  int xcd = g & 7, i7 = g >> 3;
  int wgid = (xcd==0) ? i7 : (343 + (xcd-1)*342 + i7);
  int x = wgid % 7, y = wgid / 7;

  int t = threadIdx.x;
  int wid = t >> 6, lane = t & 63;
  int q = lane >> 4, li = lane & 15;
  int row0blk = y*128;
  int col0 = x*64;
  int w32 = wid*32;

  __shared__ char lds[49152];   // [A0 16K][B0 8K][A1 16K][B1 8K]

  float4v acc[2][4];
  #pragma unroll
  for (int i=0;i<2;i++)
    #pragma unroll
    for (int j=0;j<4;j++) acc[i][j] = (float4v)(0.f);

  auto stage = [&](int st, int buf){
    const int k0 = st*64;
    char* lA = lds + (buf ? 24576 : 0);
    char* lB = lds + (buf ? 40960 : 16384);
    const bf16* Asrc = A16 + (size_t)row0blk*256 + k0;
    const bf16* Bsrc = Bp  + (size_t)col0*256 + k0;
    #pragma unroll
    for (int ra=0; ra<4; ++ra){
      int gidx = ra*256 + t;
      int r = gidx >> 3, c = gidx & 7;
      const bf16* src = Asrc + (size_t)r*256 + ((c ^ (r&7)) << 3);
      char* dst = lA + (ra*256 + wid*64)*16;   // wave-uniform base; HW adds lane*16
      __builtin_amdgcn_global_load_lds((const __attribute__((address_space(1))) void*)src,
                                       (__attribute__((address_space(3))) void*)dst, 16, 0, 0);
    }
    #pragma unroll
    for (int rb=0; rb<2; ++rb){
      int gidx = rb*256 + t;
      int r = gidx >> 3, c = gidx & 7;
      const bf16* src = Bsrc + (size_t)r*256 + ((c ^ (r&7)) << 3);
      char* dst = lB + (rb*256 + wid*64)*16;
      __builtin_amdgcn_global_load_lds((const __attribute__((address_space(1))) void*)src,
                                       (__attribute__((address_space(3))) void*)dst, 16, 0, 0);
    }
  };

  stage(0, 0);
  #pragma unroll
  for (int st=0; st<4; ++st){
    int bufc = st & 1;
    if (st < 3) stage(st+1, bufc^1);
    __builtin_amdgcn_sched_barrier(0);
    if (st < 3) asm volatile("s_waitcnt vmcnt(6)" ::: "memory");   // current tile done, next 6 in flight
    else        asm volatile("s_waitcnt vmcnt(0)" ::: "memory");
    __builtin_amdgcn_s_barrier();
    __builtin_amdgcn_sched_barrier(0);

    const char* cA = lds + (bufc ? 24576 : 0);
    const char* cB = lds + (bufc ? 40960 : 16384);
    short8 af[2][2], bfr[4][2];
    #pragma unroll
    for (int i=0;i<2;i++)
      #pragma unroll
      for (int k2=0;k2<2;k2++){
        int row = w32 + i*16 + li;
        int gr = (k2*4 + q) ^ (li & 7);
        af[i][k2] = *(const short8*)(cA + row*128 + gr*16);
      }
    #pragma unroll
    for (int j=0;j<4;j++)
      #pragma unroll
      for (int k2=0;k2<2;k2++){
        int row = j*16 + li;
        int gr = (k2*4 + q) ^ (li & 7);
        bfr[j][k2] = *(const short8*)(cB + row*128 + gr*16);
      }
    #pragma unroll
    for (int k2=0;k2<2;k2++)
      #pragma unroll
      for (int j=0;j<4;j++){
        acc[0][j] = __builtin_amdgcn_mfma_f32_16x16x32_bf16(af[0][k2], bfr[j][k2], acc[0][j],0,0,0);
        acc[1][j] = __builtin_amdgcn_mfma_f32_16x16x32_bf16(af[1][k2], bfr[j][k2], acc[1][j],0,0,0);
      }
    __builtin_amdgcn_sched_barrier(0);
    __builtin_amdgcn_s_barrier();
  }

  int row0 = row0blk + w32;
  #pragma unroll
  for (int i=0;i<2;i++){
    #pragma unroll
    for (int r=0;r<4;r++){
      int grow = row0 + i*16 + q*4 + r;
      if (grow >= N_) continue;
      #pragma unroll
      for (int j=0;j<4;j++){
        int gc = col0 + j*16 + li;
        float v = acc[i][j][r];
        if (gc < 256)      V16 [(size_t)grow*256 + gc]       = __float2bfloat16(v);  // contiguous (permuted)
        else if (gc < 384) Hb16[(size_t)grow*128 + gc - 256] = __float2bfloat16(v);
        else if (gc < 396) S   [(size_t)grow*12  + gc - 384] = v;
      }
    }
  }
}

// ---------------- per-node gate (Hb bf16) ----------------
__global__ __launch_bounds__(256) void k_gate(const unsigned short* __restrict__ Hb16, const float* __restrict__ S,
    const float* __restrict__ pre_l, const float* __restrict__ w2_l, const float* __restrict__ b2_l,
    const int* __restrict__ ntype, float* __restrict__ G){
  int node = blockIdx.x*4 + (threadIdx.x>>6);
  int lane = threadIdx.x & 63;
  if (node >= N_) return;
  int typ = ntype[node];
  const float* pr = pre_l + typ*128;
  float v0 = tanhf(u2f(Hb16[(size_t)node*128 + lane])      + pr[lane]);
  float v1 = tanhf(u2f(Hb16[(size_t)node*128 + 64 + lane]) + pr[64+lane]);
  float p0 = v0 * w2_l[lane];
  float p1 = v1 * w2_l[64+lane];
  #pragma unroll
  for (int d=1; d<32; d<<=1){ p0 += __shfl_xor(p0,d,64); p1 += __shfl_xor(p1,d,64); }
  float at0 = sigm(__shfl(p0, 0,64) + b2_l[0]);
  float at1 = sigm(__shfl(p0,32,64) + b2_l[1]);
  float at2 = sigm(__shfl(p1, 0,64) + b2_l[2]);
  float at3 = sigm(__shfl(p1,32,64) + b2_l[3]);
  if (lane < 12){
    int h = lane / 3, t = lane % 3;
    float sv = S[(size_t)node*12 + lane];
    float lr = (sv > 0.f) ? sv : 0.2f*sv;
    float av = (h==0)? at0 : (h==1)? at1 : (h==2)? at2 : at3;
    G[(size_t)node*12 + t*4 + h] = lr * av;
  }
}

// ---------------- per-edge softmax + edge_feat (single-pass, pipelined gather) ----------------
__global__ __launch_bounds__(256) void k_edge(const int* __restrict__ eoff, const int* __restrict__ ep,
    const int* __restrict__ nidx, const int* __restrict__ etype,
    const float* __restrict__ G, const unsigned short* __restrict__ V16,
    float* __restrict__ attn, unsigned short* __restrict__ EF16){
  int e = blockIdx.x*4 + (threadIdx.x>>6);
  int lane = threadIdx.x & 63;
  if (e >= E_) return;
  int beg = eoff[e], end = eoff[e+1];
  int deg = end - beg;
  if (deg == 0) return;
  int t = etype[e];
  float a0=0,a1=0,a2=0,a3=0;

  if (deg <= 64){
    int i = beg + lane;
    int m = -1, n = 0;
    float4 g; g.x=g.y=g.z=g.w=-1e30f;
    if (lane < deg){
      m = ep[i]; n = nidx[m];
      g = *(const float4*)(G + (size_t)n*12 + t*4);
    }
    float mx0=g.x, mx1=g.y, mx2=g.z, mx3=g.w;
    #pragma unroll
    for (int d=1; d<64; d<<=1){
      mx0=fmaxf(mx0,__shfl_xor(mx0,d,64)); mx1=fmaxf(mx1,__shfl_xor(mx1,d,64));
      mx2=fmaxf(mx2,__shfl_xor(mx2,d,64)); mx3=fmaxf(mx3,__shfl_xor(mx3,d,64));
    }
    float ex0=0,ex1=0,ex2=0,ex3=0;
    if (lane < deg){
      ex0=__expf(g.x-mx0); ex1=__expf(g.y-mx1); ex2=__expf(g.z-mx2); ex3=__expf(g.w-mx3);
    }
    float s0=ex0,s1=ex1,s2=ex2,s3=ex3;
    #pragma unroll
    for (int d=1; d<64; d<<=1){
      s0+=__shfl_xor(s0,d,64); s1+=__shfl_xor(s1,d,64);
      s2+=__shfl_xor(s2,d,64); s3+=__shfl_xor(s3,d,64);
    }
    float4 w; w.x=ex0/s0; w.y=ex1/s1; w.z=ex2/s2; w.w=ex3/s3;
    if (lane < deg) *(float4*)(attn + (size_t)m*4) = w;
    auto ldrow = [&](int j)->ushort4{
      int nn = __shfl(n, j, 64);
      return *(const ushort4*)(V16 + (size_t)nn*256 + (lane<<2));
    };
    ushort4 v0v,v1v,v2v,v3v;
    if (deg>0) v0v=ldrow(0);
    if (deg>1) v1v=ldrow(1);
    if (deg>2) v2v=ldrow(2);
    if (deg>3) v3v=ldrow(3);
    for (int j=0;j<deg;j+=4){
      { float wx=__shfl(w.x,j,64),wy=__shfl(w.y,j,64),wz=__shfl(w.z,j,64),wq=__shfl(w.w,j,64);
        a0+=wx*u2f(v0v.x); a1+=wy*u2f(v0v.y); a2+=wz*u2f(v0v.z); a3+=wq*u2f(v0v.w);
        if (j+4<deg) v0v=ldrow(j+4); }
      if (j+1<deg){
        float wx=__shfl(w.x,j+1,64),wy=__shfl(w.y,j+1,64),wz=__shfl(w.z,j+1,64),wq=__shfl(w.w,j+1,64);
        a0+=wx*u2f(v1v.x); a1+=wy*u2f(v1v.y); a2+=wz*u2f(v1v.z); a3+=wq*u2f(v1v.w);
        if (j+5<deg) v1v=ldrow(j+5); }
      if (j+2<deg){
        float wx=__shfl(w.x,j+2,64),wy=__shfl(w.y,j+2,64),wz=__shfl(w.z,j+2,64),wq=__shfl(w.w,j+2,64);
        a0+=wx*u2f(v2v.x); a1+=wy*u2f(v2v.y); a2+=wz*u2f(v2v.z); a3+=wq*u2f(v2v.w);
        if (j+6<deg) v2v=ldrow(j+6); }
      if (j+3<deg){
        float wx=__shfl(w.x,j+3,64),wy=__shfl(w.y,j+3,64),wz=__shfl(w.z,j+3,64),wq=__shfl(w.w,j+3,64);
        a0+=wx*u2f(v3v.x); a1+=wy*u2f(v3v.y); a2+=wz*u2f(v3v.z); a3+=wq*u2f(v3v.w);
        if (j+7<deg) v3v=ldrow(j+7); }
    }
  } else {
    float mx0=-1e30f, mx1=-1e30f, mx2=-1e30f, mx3=-1e30f;
    for (int i=beg+lane; i<end; i+=64){
      int m = ep[i]; int n = nidx[m];
      float4 g = *(const float4*)(G + (size_t)n*12 + t*4);
      mx0=fmaxf(mx0,g.x); mx1=fmaxf(mx1,g.y); mx2=fmaxf(mx2,g.z); mx3=fmaxf(mx3,g.w);
    }
    #pragma unroll
    for (int d=1; d<64; d<<=1){
      mx0=fmaxf(mx0,__shfl_xor(mx0,d,64)); mx1=fmaxf(mx1,__shfl_xor(mx1,d,64));
      mx2=fmaxf(mx2,__shfl_xor(mx2,d,64)); mx3=fmaxf(mx3,__shfl_xor(mx3,d,64));
    }
    float sm0=0,sm1=0,sm2=0,sm3=0;
    for (int i=beg+lane; i<end; i+=64){
      int m = ep[i]; int n = nidx[m];
      float4 g = *(const float4*)(G + (size_t)n*12 + t*4);
      sm0+=__expf(g.x-mx0); sm1+=__expf(g.y-mx1); sm2+=__expf(g.z-mx2); sm3+=__expf(g.w-mx3);
    }
    #pragma unroll
    for (int d=1; d<64; d<<=1){
      sm0+=__shfl_xor(sm0,d,64); sm1+=__shfl_xor(sm1,d,64);
      sm2+=__shfl_xor(sm2,d,64); sm3+=__shfl_xor(sm3,d,64);
    }
    float inv0=1.f/sm0, inv1=1.f/sm1, inv2=1.f/sm2, inv3=1.f/sm3;
    for (int i=beg+lane; i<end; i+=64){
      int m = ep[i]; int n = nidx[m];
      float4 g = *(const float4*)(G + (size_t)n*12 + t*4);
      float4 w;
      w.x=__expf(g.x-mx0)*inv0; w.y=__expf(g.y-mx1)*inv1;
      w.z=__expf(g.z-mx2)*inv2; w.w=__expf(g.w-mx3)*inv3;
      *(float4*)(attn + (size_t)m*4) = w;
    }
    for (int i=beg; i<end; ++i){
      int m = ep[i]; int n = nidx[m];
      float4 g = *(const float4*)(G + (size_t)n*12 + t*4);
      float w0=__expf(g.x-mx0)*inv0, w1=__expf(g.y-mx1)*inv1;
      float w2=__expf(g.z-mx2)*inv2, w3=__expf(g.w-mx3)*inv3;
      ushort4 v = *(const ushort4*)(V16 + (size_t)n*256 + lane*4);
      a0 += w0*u2f(v.x); a1 += w1*u2f(v.y); a2 += w2*u2f(v.z); a3 += w3*u2f(v.w);
    }
  }
  ushort4 ev; ev.x=f2u(a0); ev.y=f2u(a1); ev.z=f2u(a2); ev.w=f2u(a3);
  *(ushort4*)(EF16 + (size_t)e*256 + lane*4) = ev;
}

// ---------------- per-node gather + residual + LayerNorm (pipelined) ----------------
__global__ __launch_bounds__(256) void k_node(const int* __restrict__ noff, const int* __restrict__ np,
    const int* __restrict__ eidx, const float* __restrict__ attn, const unsigned short* __restrict__ EF16,
    const float* __restrict__ lng, const float* __restrict__ lnb,
    bf16* __restrict__ h16, void* __restrict__ outv, const int* __restrict__ flag, int last){
  int n = blockIdx.x*4 + (threadIdx.x>>6);
  int lane = threadIdx.x & 63;
  if (n >= N_) return;
  float f0=0,f1=0,f2=0,f3=0;
  int beg = noff[n], end = noff[n+1];
  int deg = end - beg;
  if (deg > 0 && deg <= 64){
    int i = beg + lane;
    int e = 0;
    float4 w; w.x=w.y=w.z=w.w=0.f;
    if (lane < deg){
      int m = np[i]; e = eidx[m];
      w = *(const float4*)(attn + (size_t)m*4);
    }
    auto ldrow = [&](int j)->ushort4{
      int ee = __shfl(e, j, 64);
      return *(const ushort4*)(EF16 + (size_t)ee*256 + (lane<<2));
    };
    ushort4 v0v,v1v,v2v,v3v;
    if (deg>0) v0v=ldrow(0);
    if (deg>1) v1v=ldrow(1);
    if (deg>2) v2v=ldrow(2);
    if (deg>3) v3v=ldrow(3);
    for (int j=0;j<deg;j+=4){
      { float wx=__shfl(w.x,j,64),wy=__shfl(w.y,j,64),wz=__shfl(w.z,j,64),wq=__shfl(w.w,j,64);
        f0+=wx*u2f(v0v.x); f1+=wy*u2f(v0v.y); f2+=wz*u2f(v0v.z); f3+=wq*u2f(v0v.w);
        if (j+4<deg) v0v=ldrow(j+4); }
      if (j+1<deg){
        float wx=__shfl(w.x,j+1,64),wy=__shfl(w.y,j+1,64),wz=__shfl(w.z,j+1,64),wq=__shfl(w.w,j+1,64);
        f0+=wx*u2f(v1v.x); f1+=wy*u2f(v1v.y); f2+=wz*u2f(v1v.z); f3+=wq*u2f(v1v.w);
        if (j+5<deg) v1v=ldrow(j+5); }
      if (j+2<deg){
        float wx=__shfl(w.x,j+2,64),wy=__shfl(w.y,j+2,64),wz=__shfl(w.z,j+2,64),wq=__shfl(w.w,j+2,64);
        f0+=wx*u2f(v2v.x); f1+=wy*u2f(v2v.y); f2+=wz*u2f(v2v.z); f3+=wq*u2f(v2v.w);
        if (j+6<deg) v2v=ldrow(j+6); }
      if (j+3<deg){
        float wx=__shfl(w.x,j+3,64),wy=__shfl(w.y,j+3,64),wz=__shfl(w.z,j+3,64),wq=__shfl(w.w,j+3,64);
        f0+=wx*u2f(v3v.x); f1+=wy*u2f(v3v.y); f2+=wz*u2f(v3v.z); f3+=wq*u2f(v3v.w);
        if (j+7<deg) v3v=ldrow(j+7); }
    }
  } else if (deg > 64){
    for (int i=beg; i<end; ++i){
      int m = np[i]; int e = eidx[m];
      float4 w = *(const float4*)(attn + (size_t)m*4);
      ushort4 v = *(const ushort4*)(EF16 + (size_t)e*256 + lane*4);
      f0 += w.x*u2f(v.x); f1 += w.y*u2f(v.y); f2 += w.z*u2f(v.z); f3 += w.w*u2f(v.w);
    }
  }
  const bf16* hp = h16 + (size_t)n*256;
  float h0 = b2f(hp[lane])+f0, h1 = b2f(hp[64+lane])+f1, h2 = b2f(hp[128+lane])+f2, h3 = b2f(hp[192+lane])+f3;
  float s = h0+h1+h2+h3;
  #pragma unroll
  for (int d=1; d<64; d<<=1) s += __shfl_xor(s,d,64);
  float mean = s * (1.f/256.f);
  float d0=h0-mean, d1=h1-mean, d2=h2-mean, d3=h3-mean;
  float vv = d0*d0+d1*d1+d2*d2+d3*d3;
  #pragma unroll
  for (int d=1; d<64; d<<=1) vv += __shfl_xor(vv,d,64);
  float rstd = rsqrtf(vv*(1.f/256.f) + 1e-5f);
  float o0 = d0*rstd*lng[lane]     + lnb[lane];
  float o1 = d1*rstd*lng[64+lane]  + lnb[64+lane];
  float o2 = d2*rstd*lng[128+lane] + lnb[128+lane];
  float o3 = d3*rstd*lng[192+lane] + lnb[192+lane];
  if (last){
    if (*flag){
      bf16* op = (bf16*)outv + (size_t)n*256;
      op[lane]=__float2bfloat16(o0); op[64+lane]=__float2bfloat16(o1);
      op[128+lane]=__float2bfloat16(o2); op[192+lane]=__float2bfloat16(o3);
    } else {
      float* op = (float*)outv + (size_t)n*256;
      op[lane]=o0; op[64+lane]=o1; op[128+lane]=o2; op[192+lane]=o3;
    }
  } else {
    bf16* o16 = h16 + (size_t)n*256;
    o16[lane]=__float2bfloat16(o0); o16[64+lane]=__float2bfloat16(o1);
    o16[128+lane]=__float2bfloat16(o2); o16[192+lane]=__float2bfloat16(o3);
  }
}

extern "C" void kernel_launch(void* const* d_in, const int* in_sizes, int n_in,
                              void* d_out, int out_size, void* d_ws, size_t ws_size,
                              hipStream_t stream){
  const void* x    = d_in[0];
  const int* ntype = (const int*)d_in[1];
  const int* etype = (const int*)d_in[2];
  const int* nidx  = (const int*)d_in[3];
  const int* eidx  = (const int*)d_in[4];
  (void)in_sizes; (void)n_in; (void)out_size; (void)ws_size;

  char* ws = (char*)d_ws;
  size_t o = 0;
  auto alloc = [&](size_t b)->char*{ char* r = ws + o; o = (o + b + 255) & ~(size_t)255; return r; };
  int*   flag = (int*)  alloc(256);
  char*  R2   =         alloc((size_t)20000000);          // Hb16+S (gemm->gate) / attn+EF16 (edge->node)
  float* G    = (float*)alloc((size_t)N_*12*4);
  float* tq_f  = (float*)alloc(1536*4);
  float* w1_f  = (float*)alloc(81920*4);
  float* b1_f  = (float*)alloc(256*4);
  float* w2_f  = (float*)alloc(256*4);
  float* b2_f  = (float*)alloc(8*4);
  float* wq_f  = (float*)alloc(131072*4);
  float* wv_f  = (float*)alloc(131072*4);
  float* ec_f  = (float*)alloc(1536*4);
  float* lng_f = (float*)alloc(512*4);
  float* lnb_f = (float*)alloc(512*4);
  float* pre   = (float*)alloc(768*4);
  int* cnt_e  = (int*)alloc((size_t)NREP_*E_*4);
  int* cnt_n  = (int*)alloc((size_t)NREP_*N_*4);
  int* eoff   = (int*)alloc((size_t)(E_+1)*4);
  int* noff   = (int*)alloc((size_t)(N_+1)*4);
  int* cur_e  = (int*)alloc((size_t)E_*4);
  int* cur_n  = (int*)alloc((size_t)N_*4);
  int* ep     = (int*)alloc((size_t)M_*4);
  int* np     = (int*)alloc((size_t)M_*4);
  int* bsum_e = (int*)alloc(256*4);
  int* bsum_n = (int*)alloc(256*4);
  bf16* h16   = (bf16*)alloc((size_t)NPAD_*256*2);        // 25.6 MB bf16 hidden state (A for MFMA)
  bf16* Bp    = (bf16*)alloc((size_t)2*448*256*2);
  bf16* V16   = (bf16*)alloc((size_t)N_*256*2);           // 25.6 MB interleaved [n][d][h]

  bf16*  Hb16 = (bf16*)R2;                                 // 12.8 MB
  float* S    = (float*)(R2 + 16777216);                   // 2.4 MB
  float* attn = (float*)R2;                                // 5.12 MB
  unsigned short* EF16 = (unsigned short*)(R2 + 5242880);  // 10.24 MB (ends 15.48M < S)

  // launch 1: sniff + zero replicated counters (8*70000 = 560000 ints)
  k_sniffzero<<<1 + (NREP_*(E_+N_)+255)/256, 256, 0, stream>>>((const unsigned short*)x, flag, cnt_e, cnt_n);
  // launch 2: hist(first, replicated) + cvtall + cvt16(vectorized)
  k_prep<<<HISTB_+CVTALLB_+CVTB_, 256, 0, stream>>>(
      x, h16,
      d_in[5], d_in[6], d_in[7], d_in[8], d_in[9],
      d_in[10], d_in[11], d_in[12], d_in[13], d_in[14],
      tq_f, w1_f, b1_f, w2_f, b2_f, wq_f, wv_f, ec_f, lng_f, lnb_f,
      eidx, nidx, cnt_e, cnt_n, flag);
  // launch 3: scan phase 1 (sums 8 replicas) + pre + bpack(with inline wqe)
  k_scan1w<<<NB_E+NB_N+3+896, 256, 0, stream>>>(
      cnt_e, eoff, bsum_e, cnt_n, noff, bsum_n,
      tq_f, w1_f, b1_f, pre, wv_f, wq_f, ec_f, Bp);
  // launch 4: scan phases 2+3
  k_scan23<<<NB_E+NB_N, 256, 0, stream>>>(bsum_e, eoff, cur_e, bsum_n, noff, cur_n);
  // launch 5: fill CSR
  k_fill<<<M_/256, 256, 0, stream>>>(eidx, nidx, cur_e, cur_n, ep, np);

  for (int l=0; l<2; ++l){
    k_mgemm<<<2737, 256, 0, stream>>>(h16, Bp + (size_t)l*448*256, V16, Hb16, S);
    k_gate<<<12500, 256, 0, stream>>>((const unsigned short*)Hb16, S, pre + l*384,
                                      w2_f + l*128, b2_f + l*4, ntype, G);
    k_edge<<<5000, 256, 0, stream>>>(eoff, ep, nidx, etype, G, (const unsigned short*)V16, attn, EF16);
    k_node<<<12500, 256, 0, stream>>>(noff, np, eidx, attn, EF16, lng_f + l*256, lnb_f + l*256,
                                      h16, d_out, flag, l==1);
  }
}